// Round 2
// baseline (3384.284 us; speedup 1.0000x reference)
//
#include <hip/hip_runtime.h>
#include <math.h>

// ---- problem constants ----
#define NN     50000
#define NE     400000
#define INDIM  256
#define NH     128
#define NTYPE  4
#define NREL   5
#define NHEAD  4
#define DK     32
#define RSQRT_DK 0.17677669529663687f
#define BN     64
#define NSCAN_BLK ((NN + 255) / 256)   // 196

__device__ __forceinline__ float gelu_f(float x){
    return 0.5f * x * (1.0f + erff(x * 0.70710678118654752f));
}

// ---------------- node bucketing by type (for per-type GEMMs) ----------------
__global__ void GNN_nscatter(const int* __restrict__ ntype, int* __restrict__ ncur,
                             int* __restrict__ nperm){
    __shared__ int lcnt[4], lbase[4];
    int tid = threadIdx.x;
    if (tid < 4) lcnt[tid] = 0;
    __syncthreads();
    int n = blockIdx.x * 256 + tid;
    int t = 0, lpos = 0;
    bool ok = (n < NN);
    if (ok){ t = ntype[n]; lpos = atomicAdd(&lcnt[t], 1); }
    __syncthreads();
    if (tid < 4 && lcnt[tid] > 0) lbase[tid] = atomicAdd(&ncur[tid], lcnt[tid]);
    __syncthreads();
    if (ok) nperm[t * NN + lbase[t] + lpos] = n;
}

// ---------------- CSR by destination (built once per call) ----------------
__global__ void GNN_deg(const int* __restrict__ edst, int* __restrict__ deg){
    int e = blockIdx.x * 256 + threadIdx.x;
    if (e < NE) atomicAdd(&deg[edst[e]], 1);
}

__global__ void GNN_scan1(const int* __restrict__ deg, int* __restrict__ rowptr,
                          int* __restrict__ bsum){
    __shared__ int s[256];
    int g = blockIdx.x * 256 + threadIdx.x;
    int v = (g < NN) ? deg[g] : 0;
    s[threadIdx.x] = v;
    __syncthreads();
    for (int off = 1; off < 256; off <<= 1){
        int t = (threadIdx.x >= off) ? s[threadIdx.x - off] : 0;
        __syncthreads();
        s[threadIdx.x] += t;
        __syncthreads();
    }
    if (g < NN) rowptr[g] = s[threadIdx.x] - v;           // block-local exclusive
    if (threadIdx.x == 255) bsum[blockIdx.x] = s[255];
}

__global__ void GNN_scan2(const int* __restrict__ bsum, int* __restrict__ bbase){
    __shared__ int s[256];
    int v = (threadIdx.x < NSCAN_BLK) ? bsum[threadIdx.x] : 0;
    s[threadIdx.x] = v;
    __syncthreads();
    for (int off = 1; off < 256; off <<= 1){
        int t = (threadIdx.x >= off) ? s[threadIdx.x - off] : 0;
        __syncthreads();
        s[threadIdx.x] += t;
        __syncthreads();
    }
    bbase[threadIdx.x] = s[threadIdx.x] - v;              // exclusive
}

__global__ void GNN_scan3(int* __restrict__ rowptr, const int* __restrict__ bbase){
    int g = blockIdx.x * 256 + threadIdx.x;
    if (g < NN) rowptr[g] += bbase[blockIdx.x];
    if (g == 0) rowptr[NN] = NE;
}

__global__ void GNN_csr_scatter(const int* __restrict__ edst, const int* __restrict__ rowptr,
                                int* __restrict__ cursor, int* __restrict__ csr_e){
    int e = blockIdx.x * 256 + threadIdx.x;
    if (e >= NE) return;
    int d = edst[e];
    int pos = atomicAdd(&cursor[d], 1);
    csr_e[rowptr[d] + pos] = e;
}

// ------------- per-type tiled GEMM: OUT[n,:] = epilogue( X[n,:] @ W[type(n)] + b[type(n)] )
// MODE 0: gelu(.)   MODE 1: identity   MODE 2: (.)*sig(skip[t]) + Hprev*(1-sig(skip[t]))
// v3: 128 threads (2 waves), thread = 8 rows x 8 cols (col groups {4cq, 64+4cq}),
//     all-float4 LDS reads (Xs broadcast, Ws contiguous-span), register prefetch of
//     the next k-tile. All LDS patterns <=2 addrs/bank per 16-lane quarter (free).
template<int MODE>
__global__ __launch_bounds__(128) void GNN_ptype_gemm(
    const float* __restrict__ X, int K,
    const float* __restrict__ Wall, const float* __restrict__ ball,
    const float* __restrict__ skiprow, const float* __restrict__ Hprev,
    const int* __restrict__ nperm, const int* __restrict__ counts,
    float* __restrict__ OUT)
{
    int t = blockIdx.y;
    int cnt = counts[t];
    int rbase = blockIdx.x * BN;
    if (rbase >= cnt) return;
    const float* W = Wall + (size_t)t * K * NH;
    __shared__ float Xs[64 * 36];          // stride 36 words (16B aligned, bank-spread)
    __shared__ float Ws[32 * 128];
    __shared__ int nids[BN];
    int tid = threadIdx.x;
    if (tid < BN){
        int idx = rbase + tid;
        nids[tid] = (idx < cnt) ? nperm[t * NN + idx] : -1;
    }
    __syncthreads();

    float4 xr[4], wr[8];
    // Xs staging slots: slot = j*128+tid -> row = slot>>3, c4 = slot&7   (64x8 float4)
    // Ws staging slots: slot = j*128+tid -> kk = slot>>5, col4 = slot&31 (32x32 float4)
    auto loadX = [&](int k0){
        #pragma unroll
        for (int j = 0; j < 4; j++){
            int slot = j * 128 + tid;
            int row = slot >> 3, c4 = slot & 7;
            int nid = nids[row];
            xr[j] = make_float4(0.f, 0.f, 0.f, 0.f);
            if (nid >= 0) xr[j] = *(const float4*)(X + (size_t)nid * K + k0 + c4 * 4);
        }
    };
    auto loadW = [&](int k0){
        #pragma unroll
        for (int j = 0; j < 8; j++){
            int slot = j * 128 + tid;
            wr[j] = *(const float4*)(W + (size_t)(k0 + (slot >> 5)) * NH + (slot & 31) * 4);
        }
    };

    int cq = tid & 15, rq = tid >> 4;
    float accA[8][4], accB[8][4];
    #pragma unroll
    for (int i = 0; i < 8; i++){
        accA[i][0]=0.f; accA[i][1]=0.f; accA[i][2]=0.f; accA[i][3]=0.f;
        accB[i][0]=0.f; accB[i][1]=0.f; accB[i][2]=0.f; accB[i][3]=0.f;
    }

    loadX(0); loadW(0);
    for (int k0 = 0; k0 < K; k0 += 32){
        #pragma unroll
        for (int j = 0; j < 4; j++){
            int slot = j * 128 + tid;
            int row = slot >> 3, c4 = slot & 7;
            *(float4*)&Xs[row * 36 + c4 * 4] = xr[j];
        }
        #pragma unroll
        for (int j = 0; j < 8; j++){
            int slot = j * 128 + tid;
            *(float4*)&Ws[slot * 4] = wr[j];
        }
        __syncthreads();
        if (k0 + 32 < K){ loadX(k0 + 32); loadW(k0 + 32); }  // prefetch under compute
        #pragma unroll
        for (int c4 = 0; c4 < 8; c4++){
            float4 w0A = *(const float4*)&Ws[(c4*4+0)*128 + cq*4];
            float4 w1A = *(const float4*)&Ws[(c4*4+1)*128 + cq*4];
            float4 w2A = *(const float4*)&Ws[(c4*4+2)*128 + cq*4];
            float4 w3A = *(const float4*)&Ws[(c4*4+3)*128 + cq*4];
            float4 w0B = *(const float4*)&Ws[(c4*4+0)*128 + cq*4 + 64];
            float4 w1B = *(const float4*)&Ws[(c4*4+1)*128 + cq*4 + 64];
            float4 w2B = *(const float4*)&Ws[(c4*4+2)*128 + cq*4 + 64];
            float4 w3B = *(const float4*)&Ws[(c4*4+3)*128 + cq*4 + 64];
            #pragma unroll
            for (int i = 0; i < 8; i++){
                float4 xv = *(const float4*)&Xs[(rq + 8*i) * 36 + c4 * 4];
                accA[i][0] += xv.x*w0A.x + xv.y*w1A.x + xv.z*w2A.x + xv.w*w3A.x;
                accA[i][1] += xv.x*w0A.y + xv.y*w1A.y + xv.z*w2A.y + xv.w*w3A.y;
                accA[i][2] += xv.x*w0A.z + xv.y*w1A.z + xv.z*w2A.z + xv.w*w3A.z;
                accA[i][3] += xv.x*w0A.w + xv.y*w1A.w + xv.z*w2A.w + xv.w*w3A.w;
                accB[i][0] += xv.x*w0B.x + xv.y*w1B.x + xv.z*w2B.x + xv.w*w3B.x;
                accB[i][1] += xv.x*w0B.y + xv.y*w1B.y + xv.z*w2B.y + xv.w*w3B.y;
                accB[i][2] += xv.x*w0B.z + xv.y*w1B.z + xv.z*w2B.z + xv.w*w3B.z;
                accB[i][3] += xv.x*w0B.w + xv.y*w1B.w + xv.z*w2B.w + xv.w*w3B.w;
            }
        }
        __syncthreads();
    }

    int colA = cq * 4, colB = cq * 4 + 64;
    float4 bA = *(const float4*)(ball + t * NH + colA);
    float4 bB = *(const float4*)(ball + t * NH + colB);
    float a_t = 0.f, one_m = 0.f;
    if (MODE == 2){ a_t = 1.f / (1.f + expf(-skiprow[t])); one_m = 1.f - a_t; }
    #pragma unroll
    for (int i = 0; i < 8; i++){
        int r = rq + 8*i;
        int nid = nids[r];
        if (nid < 0) continue;
        float vA0 = accA[i][0] + bA.x, vA1 = accA[i][1] + bA.y;
        float vA2 = accA[i][2] + bA.z, vA3 = accA[i][3] + bA.w;
        float vB0 = accB[i][0] + bB.x, vB1 = accB[i][1] + bB.y;
        float vB2 = accB[i][2] + bB.z, vB3 = accB[i][3] + bB.w;
        if (MODE == 0){
            vA0 = gelu_f(vA0); vA1 = gelu_f(vA1); vA2 = gelu_f(vA2); vA3 = gelu_f(vA3);
            vB0 = gelu_f(vB0); vB1 = gelu_f(vB1); vB2 = gelu_f(vB2); vB3 = gelu_f(vB3);
        }
        if (MODE == 2){
            float4 hpA = *(const float4*)(Hprev + (size_t)nid * NH + colA);
            float4 hpB = *(const float4*)(Hprev + (size_t)nid * NH + colB);
            vA0 = vA0 * a_t + hpA.x * one_m; vA1 = vA1 * a_t + hpA.y * one_m;
            vA2 = vA2 * a_t + hpA.z * one_m; vA3 = vA3 * a_t + hpA.w * one_m;
            vB0 = vB0 * a_t + hpB.x * one_m; vB1 = vB1 * a_t + hpB.y * one_m;
            vB2 = vB2 * a_t + hpB.z * one_m; vB3 = vB3 * a_t + hpB.w * one_m;
        }
        *(float4*)(OUT + (size_t)nid * NH + colA) = make_float4(vA0, vA1, vA2, vA3);
        *(float4*)(OUT + (size_t)nid * NH + colB) = make_float4(vB0, vB1, vB2, vB3);
    }
}

// ------------- RTE tables ----------------
__global__ void GNN_rte_tab(const float* __restrict__ rte_emb, const float* __restrict__ rW,
                            const float* __restrict__ rb, float* __restrict__ tab){
    int m = blockIdx.x, j = threadIdx.x;
    __shared__ float e[NH];
    e[j] = rte_emb[m * NH + j];
    __syncthreads();
    float a = rb[j];
    #pragma unroll 8
    for (int d = 0; d < NH; d++) a += e[d] * rW[d * NH + j];
    tab[m * NH + j] = a;
}

__global__ void GNN_rte_proj(const float* __restrict__ tab, const float* __restrict__ WkL,
                             const float* __restrict__ WvL, float* __restrict__ RK,
                             float* __restrict__ RV){
    int m = blockIdx.x, j = threadIdx.x;
    int sel = blockIdx.y; int t = sel >> 1; int which = sel & 1;
    const float* W = (which ? WvL : WkL) + (size_t)t * NH * NH;
    float* O = which ? RV : RK;
    __shared__ float e[NH];
    e[j] = tab[m * NH + j];
    __syncthreads();
    float a = 0.f;
    #pragma unroll 8
    for (int d = 0; d < NH; d++) a += e[d] * W[d * NH + j];
    O[(size_t)(t * 240 + m) * NH + j] = a;
}

// ------------- QA[r][i][h*32+d] = sum_c rel_att[r][h][d][c] * q[i][h*32+c] -----------
// Conflict-free LDS layouts:
//   Qs word index = row*144 + h*36 + c
//   Atp word index = h*1072 + nq*132 + c*4 + j  == A[h][d=nq*4+j][c]
__global__ __launch_bounds__(256) void GNN_qa(
    const float* __restrict__ Qn, const float* __restrict__ relA, float* __restrict__ QA)
{
    __shared__ float Atp[4 * 1072];        // 17152 B
    __shared__ float Qs[64 * 144];         // 36864 B
    int r = blockIdx.y;
    int nb = blockIdx.x * 64;
    int tid = threadIdx.x;
    const float* Ar = relA + (size_t)r * NHEAD * DK * DK;
    for (int x = tid; x < NHEAD * DK * DK; x += 256){
        int hh = x >> 10, rem = x & 1023, dd = rem >> 5, cc = rem & 31;
        Atp[hh * 1072 + (dd >> 2) * 132 + cc * 4 + (dd & 3)] = Ar[x];
    }
    for (int x = tid; x < 64 * 32; x += 256){
        int row = x >> 5, c4w = (x & 31) * 4;
        int hh = c4w >> 5, cc = c4w & 31;
        int node = nb + row;
        float4 qv = make_float4(0.f, 0.f, 0.f, 0.f);
        if (node < NN) qv = *(const float4*)(Qn + (size_t)node * NH + c4w);
        *(float4*)&Qs[row * 144 + hh * 36 + cc] = qv;
    }
    __syncthreads();
    int cq = tid & 31, rq = tid >> 5;
    int h = cq >> 3;
    int abase = h * 1072 + (cq & 7) * 132;
    int qbase = h * 36;
    float acc[8][4];
    #pragma unroll
    for (int i = 0; i < 8; i++){ acc[i][0]=0.f; acc[i][1]=0.f; acc[i][2]=0.f; acc[i][3]=0.f; }
    #pragma unroll 2
    for (int c4 = 0; c4 < 8; c4++){
        float4 av0 = *(const float4*)&Atp[abase + c4 * 16 + 0];
        float4 av1 = *(const float4*)&Atp[abase + c4 * 16 + 4];
        float4 av2 = *(const float4*)&Atp[abase + c4 * 16 + 8];
        float4 av3 = *(const float4*)&Atp[abase + c4 * 16 + 12];
        #pragma unroll
        for (int i = 0; i < 8; i++){
            float4 qv = *(const float4*)&Qs[(rq + 8*i) * 144 + qbase + c4 * 4];
            acc[i][0] += qv.x*av0.x + qv.y*av1.x + qv.z*av2.x + qv.w*av3.x;
            acc[i][1] += qv.x*av0.y + qv.y*av1.y + qv.z*av2.y + qv.w*av3.y;
            acc[i][2] += qv.x*av0.z + qv.y*av1.z + qv.z*av2.z + qv.w*av3.z;
            acc[i][3] += qv.x*av0.w + qv.y*av1.w + qv.z*av2.w + qv.w*av3.w;
        }
    }
    #pragma unroll
    for (int i = 0; i < 8; i++){
        int node = nb + rq + 8*i;
        if (node >= NN) continue;
        *(float4*)(QA + ((size_t)r * NN + node) * NH + cq * 4) =
            make_float4(acc[i][0], acc[i][1], acc[i][2], acc[i][3]);
    }
}

// ------------- E1: att[e,h] = (Kn[src]+RK[st,tm]) . QA[r][dst]  (32 lanes/edge, no LDS) ----
__global__ __launch_bounds__(256) void GNN_edge_att(
    const float* __restrict__ Kn, const float* __restrict__ RK, const float* __restrict__ QA,
    const int* __restrict__ esrc, const int* __restrict__ edst,
    const int* __restrict__ etype, const int* __restrict__ etime,
    const int* __restrict__ ntype, const float* __restrict__ relP,
    float* __restrict__ att)
{
    int tid = threadIdx.x;
    int e = blockIdx.x * 8 + (tid >> 5);
    if (e >= NE) return;
    int lane = tid & 31;
    int s = esrc[e], d = edst[e], r = etype[e], tm = etime[e];
    int st = ntype[s];
    float4 k4 = *(const float4*)(Kn + (size_t)s * NH + lane * 4);
    float4 rk = *(const float4*)(RK + (size_t)(st * 240 + tm) * NH + lane * 4);
    float4 qa = *(const float4*)(QA + ((size_t)r * NN + d) * NH + lane * 4);
    float pv = (k4.x + rk.x) * qa.x + (k4.y + rk.y) * qa.y
             + (k4.z + rk.z) * qa.z + (k4.w + rk.w) * qa.w;
    pv += __shfl_xor(pv, 4);
    pv += __shfl_xor(pv, 2);
    pv += __shfl_xor(pv, 1);
    if ((lane & 7) == 0){
        int head = lane >> 3;
        att[(size_t)e * NHEAD + head] = pv * relP[r * NHEAD + head] * RSQRT_DK;
    }
}

// ------------- E2a: per-node softmax + per-relation aggregation of raw v (no atomics) -----
__global__ __launch_bounds__(256) void GNN_node_aggr(
    const float* __restrict__ att, const float* __restrict__ Vn, const float* __restrict__ RV,
    const int* __restrict__ rowptr, const int* __restrict__ csr_e,
    const int* __restrict__ esrc, const int* __restrict__ etype,
    const int* __restrict__ etime, const int* __restrict__ ntype,
    float* __restrict__ P)
{
    int tid = threadIdx.x;
    int i = blockIdx.x * 8 + (tid >> 5);
    if (i >= NN) return;
    int lane = tid & 31;
    int head = lane >> 3;
    int beg = rowptr[i], end = rowptr[i + 1];
    // pass 1: segment max (all 8 lanes of a head read the same att value)
    float mx = -3.4e38f;
    for (int k = beg; k < end; k++){
        int e = csr_e[k];
        mx = fmaxf(mx, att[(size_t)e * NHEAD + head]);
    }
    // pass 2: accumulate exp-weighted raw v per relation, in registers
    float4 acc[NREL];
    #pragma unroll
    for (int rr = 0; rr < NREL; rr++) acc[rr] = make_float4(0.f, 0.f, 0.f, 0.f);
    float den = 0.f;
    for (int k = beg; k < end; k++){
        int e = csr_e[k];
        int s = esrc[e], r = etype[e], tm = etime[e];
        int st = ntype[s];
        float ex = expf(att[(size_t)e * NHEAD + head] - mx);
        den += ex;
        float4 v4 = *(const float4*)(Vn + (size_t)s * NH + lane * 4);
        float4 rv = *(const float4*)(RV + (size_t)(st * 240 + tm) * NH + lane * 4);
        float vx = v4.x + rv.x, vy = v4.y + rv.y, vz = v4.z + rv.z, vw = v4.w + rv.w;
        #pragma unroll
        for (int rr = 0; rr < NREL; rr++){
            float w = (rr == r) ? ex : 0.f;     // predicated, keeps acc in registers
            acc[rr].x += w * vx; acc[rr].y += w * vy;
            acc[rr].z += w * vz; acc[rr].w += w * vw;
        }
    }
    float inv = 1.f / (den + 1e-16f);
    #pragma unroll
    for (int rr = 0; rr < NREL; rr++){
        *(float4*)(P + ((size_t)rr * NN + i) * NH + lane * 4) =
            make_float4(acc[rr].x * inv, acc[rr].y * inv, acc[rr].z * inv, acc[rr].w * inv);
    }
}

// ------------- E2b: aggr[i][h*32+c] = gelu( sum_r sum_d P[r][i][h*32+d] * M_r[h][d][c] ) ---
//   Msp[h*1072 + nq*132 + d*4 + j] = M[h][d][c = nq*4+j]
__global__ __launch_bounds__(256) void GNN_pm(
    const float* __restrict__ P, const float* __restrict__ relM, float* __restrict__ aggr)
{
    __shared__ float Msp[4 * 1072];
    __shared__ float Ps[64 * 144];
    int tid = threadIdx.x;
    int nb = blockIdx.x * 64;
    int cq = tid & 31, rq = tid >> 5;
    int h = cq >> 3;
    int mbase = h * 1072 + (cq & 7) * 132;
    int pbase = h * 36;
    float acc[8][4];
    #pragma unroll
    for (int i = 0; i < 8; i++){ acc[i][0]=0.f; acc[i][1]=0.f; acc[i][2]=0.f; acc[i][3]=0.f; }
    for (int r = 0; r < NREL; r++){
        const float* Mr = relM + (size_t)r * NHEAD * DK * DK;
        for (int x = tid; x < NHEAD * DK * DK; x += 256){
            int hh = x >> 10, rem = x & 1023, dd = rem >> 5, kk = rem & 31;
            Msp[hh * 1072 + (kk >> 2) * 132 + dd * 4 + (kk & 3)] = Mr[x];
        }
        for (int x = tid; x < 64 * 32; x += 256){
            int row = x >> 5, c4w = (x & 31) * 4;
            int hh = c4w >> 5, cc = c4w & 31;
            int node = nb + row;
            float4 pv = make_float4(0.f, 0.f, 0.f, 0.f);
            if (node < NN) pv = *(const float4*)(P + ((size_t)r * NN + node) * NH + c4w);
            *(float4*)&Ps[row * 144 + hh * 36 + cc] = pv;
        }
        __syncthreads();
        #pragma unroll 2
        for (int d4 = 0; d4 < 8; d4++){
            float4 mv0 = *(const float4*)&Msp[mbase + d4 * 16 + 0];
            float4 mv1 = *(const float4*)&Msp[mbase + d4 * 16 + 4];
            float4 mv2 = *(const float4*)&Msp[mbase + d4 * 16 + 8];
            float4 mv3 = *(const float4*)&Msp[mbase + d4 * 16 + 12];
            #pragma unroll
            for (int i = 0; i < 8; i++){
                float4 pv = *(const float4*)&Ps[(rq + 8*i) * 144 + pbase + d4 * 4];
                acc[i][0] += pv.x*mv0.x + pv.y*mv1.x + pv.z*mv2.x + pv.w*mv3.x;
                acc[i][1] += pv.x*mv0.y + pv.y*mv1.y + pv.z*mv2.y + pv.w*mv3.y;
                acc[i][2] += pv.x*mv0.z + pv.y*mv1.z + pv.z*mv2.z + pv.w*mv3.z;
                acc[i][3] += pv.x*mv0.w + pv.y*mv1.w + pv.z*mv2.w + pv.w*mv3.w;
            }
        }
        __syncthreads();
    }
    #pragma unroll
    for (int i = 0; i < 8; i++){
        int node = nb + rq + 8*i;
        if (node >= NN) continue;
        *(float4*)(aggr + (size_t)node * NH + cq * 4) =
            make_float4(gelu_f(acc[i][0]), gelu_f(acc[i][1]),
                        gelu_f(acc[i][2]), gelu_f(acc[i][3]));
    }
}

extern "C" void kernel_launch(void* const* d_in, const int* in_sizes, int n_in,
                              void* d_out, int out_size, void* d_ws, size_t ws_size,
                              hipStream_t stream)
{
    const float* node_feature = (const float*)d_in[0];
    const float* adapt_W = (const float*)d_in[1];
    const float* adapt_b = (const float*)d_in[2];
    const float* Wk = (const float*)d_in[3];
    const float* bk = (const float*)d_in[4];
    const float* Wq = (const float*)d_in[5];
    const float* bq = (const float*)d_in[6];
    const float* Wv = (const float*)d_in[7];
    const float* bv = (const float*)d_in[8];
    const float* Wa = (const float*)d_in[9];
    const float* ba = (const float*)d_in[10];
    const float* rel_pri = (const float*)d_in[11];
    const float* rel_att = (const float*)d_in[12];
    const float* rel_msg = (const float*)d_in[13];
    const float* skip = (const float*)d_in[14];
    const float* rte_emb = (const float*)d_in[15];
    const float* rte_W = (const float*)d_in[16];
    const float* rte_b = (const float*)d_in[17];
    const int* node_type = (const int*)d_in[18];
    const int* edge_index = (const int*)d_in[19];
    const int* edge_type = (const int*)d_in[20];
    const int* edge_time = (const int*)d_in[21];
    const int* esrc = edge_index;          // row 0 = source j
    const int* edst = edge_index + NE;     // row 1 = target i

    char* p = (char*)d_ws;
    auto alloc = [&](size_t bytes) -> char* {
        char* r = p; p += (bytes + 255) & ~(size_t)255; return r;
    };
    float* hA    = (float*)alloc((size_t)NN * NH * 4);
    float* Qn    = (float*)alloc((size_t)NN * NH * 4);      // att aliases this (E1..E2a window)
    float* Kn    = (float*)alloc((size_t)NN * NH * 4);      // aggr aliases this (E2b..Wa window)
    float* Vn    = (float*)alloc((size_t)NN * NH * 4);
    float* QA    = (float*)alloc((size_t)NREL * NN * NH * 4);  // P aliases this (E2a..E2b)
    float* rtab  = (float*)alloc((size_t)240 * NH * 4);
    float* RK    = (float*)alloc((size_t)NTYPE * 240 * NH * 4);
    float* RV    = (float*)alloc((size_t)NTYPE * 240 * NH * 4);
    int* nperm   = (int*)alloc((size_t)NTYPE * NN * 4);
    int* rowptr  = (int*)alloc((size_t)(NN + 1) * 4);
    int* csr_e   = (int*)alloc((size_t)NE * 4);
    int* deg     = (int*)alloc((size_t)2 * NN * 4);   // deg+cursor in ONE block: the single
    int* cursor  = deg + NN;                          // memset covers both exactly
    int* bsum    = (int*)alloc(256 * 4);
    int* bbase   = (int*)alloc(256 * 4);
    int* ncur    = (int*)alloc(64);
    float* att   = Qn;      // [NE*NHEAD] = 6.4 MB < 25.6 MB
    float* Pbuf  = QA;      // per-(relation,node) aggregate
    float* aggr  = Kn;

    hipMemsetAsync(ncur, 0, 64, stream);
    hipMemsetAsync(deg, 0, (size_t)2 * NN * 4, stream);     // covers deg AND cursor exactly

    GNN_nscatter<<<(NN + 255) / 256, 256, 0, stream>>>(node_type, ncur, nperm);
    GNN_deg<<<(NE + 255) / 256, 256, 0, stream>>>(edst, deg);
    GNN_scan1<<<NSCAN_BLK, 256, 0, stream>>>(deg, rowptr, bsum);
    GNN_scan2<<<1, 256, 0, stream>>>(bsum, bbase);
    GNN_scan3<<<NSCAN_BLK, 256, 0, stream>>>(rowptr, bbase);
    GNN_csr_scatter<<<(NE + 255) / 256, 256, 0, stream>>>(edst, rowptr, cursor, csr_e);

    dim3 ggrid((NN + BN - 1) / BN, NTYPE);
    GNN_ptype_gemm<0><<<ggrid, 128, 0, stream>>>(node_feature, INDIM, adapt_W, adapt_b,
                                                 nullptr, nullptr, nperm, ncur, hA);
    const float* hin = hA;
    for (int l = 0; l < 2; l++){
        const float* WkL = Wk + (size_t)l * NTYPE * NH * NH;
        const float* WqL = Wq + (size_t)l * NTYPE * NH * NH;
        const float* WvL = Wv + (size_t)l * NTYPE * NH * NH;
        const float* WaL = Wa + (size_t)l * NTYPE * NH * NH;
        const float* bkL = bk + (size_t)l * NTYPE * NH;
        const float* bqL = bq + (size_t)l * NTYPE * NH;
        const float* bvL = bv + (size_t)l * NTYPE * NH;
        const float* baL = ba + (size_t)l * NTYPE * NH;
        const float* relA = rel_att + (size_t)l * NREL * NHEAD * DK * DK;
        const float* relM = rel_msg + (size_t)l * NREL * NHEAD * DK * DK;
        const float* relP = rel_pri + (size_t)l * NREL * NHEAD;

        GNN_rte_tab<<<240, 128, 0, stream>>>(rte_emb, rte_W + (size_t)l * NH * NH,
                                             rte_b + (size_t)l * NH, rtab);
        GNN_rte_proj<<<dim3(240, NTYPE * 2), 128, 0, stream>>>(rtab, WkL, WvL, RK, RV);

        GNN_ptype_gemm<1><<<ggrid, 128, 0, stream>>>(hin, NH, WqL, bqL, nullptr, nullptr,
                                                     nperm, ncur, Qn);
        GNN_qa<<<dim3((NN + 63) / 64, NREL), 256, 0, stream>>>(Qn, relA, QA);
        GNN_ptype_gemm<1><<<ggrid, 128, 0, stream>>>(hin, NH, WkL, bkL, nullptr, nullptr,
                                                     nperm, ncur, Kn);
        GNN_ptype_gemm<1><<<ggrid, 128, 0, stream>>>(hin, NH, WvL, bvL, nullptr, nullptr,
                                                     nperm, ncur, Vn);

        GNN_edge_att<<<(NE + 7) / 8, 256, 0, stream>>>(
            Kn, RK, QA, esrc, edst, edge_type, edge_time, node_type, relP, att);

        GNN_node_aggr<<<(NN + 7) / 8, 256, 0, stream>>>(
            att, Vn, RV, rowptr, csr_e, esrc, edge_type, edge_time, node_type, Pbuf);

        GNN_pm<<<(NN + 63) / 64, 256, 0, stream>>>(Pbuf, relM, aggr);

        float* hout = (l == 0) ? hA : (float*)d_out;   // l==0 in-place on hA is safe:
        GNN_ptype_gemm<2><<<ggrid, 128, 0, stream>>>(  // epilogue reads Hprev[nid,cols] then
            aggr, NH, WaL, baL, skip + (size_t)l * NTYPE, hin,   // writes same elems, same thread
            nperm, ncur, hout);
        hin = hout;
    }
}

// Round 3
// 1155.686 us; speedup vs baseline: 2.9284x; 2.9284x over previous
//
#include <hip/hip_runtime.h>
#include <math.h>

// ---- problem constants ----
#define NN     50000
#define NE     400000
#define INDIM  256
#define NH     128
#define NTYPE  4
#define NREL   5
#define NHEAD  4
#define DK     32
#define RSQRT_DK 0.17677669529663687f
#define BN     64
#define NSCAN_BLK ((NN + 255) / 256)   // 196
#define XB     260                     // Xs c4-block stride in words (260*4B, 16B-aligned)

__device__ __forceinline__ float gelu_f(float x){
    return 0.5f * x * (1.0f + erff(x * 0.70710678118654752f));
}

// ---------------- node bucketing by type (for per-type GEMMs) ----------------
__global__ void GNN_nscatter(const int* __restrict__ ntype, int* __restrict__ ncur,
                             int* __restrict__ nperm){
    __shared__ int lcnt[4], lbase[4];
    int tid = threadIdx.x;
    if (tid < 4) lcnt[tid] = 0;
    __syncthreads();
    int n = blockIdx.x * 256 + tid;
    int t = 0, lpos = 0;
    bool ok = (n < NN);
    if (ok){ t = ntype[n]; lpos = atomicAdd(&lcnt[t], 1); }
    __syncthreads();
    if (tid < 4 && lcnt[tid] > 0) lbase[tid] = atomicAdd(&ncur[tid], lcnt[tid]);
    __syncthreads();
    if (ok) nperm[t * NN + lbase[t] + lpos] = n;
}

// ---------------- CSR by destination (built once per call) ----------------
__global__ void GNN_deg(const int* __restrict__ edst, int* __restrict__ deg){
    int e = blockIdx.x * 256 + threadIdx.x;
    if (e < NE) atomicAdd(&deg[edst[e]], 1);
}

__global__ void GNN_scan1(const int* __restrict__ deg, int* __restrict__ rowptr,
                          int* __restrict__ bsum){
    __shared__ int s[256];
    int g = blockIdx.x * 256 + threadIdx.x;
    int v = (g < NN) ? deg[g] : 0;
    s[threadIdx.x] = v;
    __syncthreads();
    for (int off = 1; off < 256; off <<= 1){
        int t = (threadIdx.x >= off) ? s[threadIdx.x - off] : 0;
        __syncthreads();
        s[threadIdx.x] += t;
        __syncthreads();
    }
    if (g < NN) rowptr[g] = s[threadIdx.x] - v;           // block-local exclusive
    if (threadIdx.x == 255) bsum[blockIdx.x] = s[255];
}

__global__ void GNN_scan2(const int* __restrict__ bsum, int* __restrict__ bbase){
    __shared__ int s[256];
    int v = (threadIdx.x < NSCAN_BLK) ? bsum[threadIdx.x] : 0;
    s[threadIdx.x] = v;
    __syncthreads();
    for (int off = 1; off < 256; off <<= 1){
        int t = (threadIdx.x >= off) ? s[threadIdx.x - off] : 0;
        __syncthreads();
        s[threadIdx.x] += t;
        __syncthreads();
    }
    bbase[threadIdx.x] = s[threadIdx.x] - v;              // exclusive
}

__global__ void GNN_scan3(int* __restrict__ rowptr, const int* __restrict__ bbase){
    int g = blockIdx.x * 256 + threadIdx.x;
    if (g < NN) rowptr[g] += bbase[blockIdx.x];
    if (g == 0) rowptr[NN] = NE;
}

__global__ void GNN_csr_scatter(const int* __restrict__ edst, const int* __restrict__ rowptr,
                                int* __restrict__ cursor, int* __restrict__ csr_e){
    int e = blockIdx.x * 256 + threadIdx.x;
    if (e >= NE) return;
    int d = edst[e];
    int pos = atomicAdd(&cursor[d], 1);
    csr_e[rowptr[d] + pos] = e;
}

// ------------- shared GEMM tile core: 256 threads, 64 rows x 128 cols, 8x4 per thread.
// Xs layout: c4-block-major, word = c4*XB + row*4  (staging writes wave-contiguous 1KB,
//   reads are 2-address 16B broadcasts on disjoint banks).  Ws: [32][128] contiguous
//   (staging + reads both the round-1 pattern measured at 0 conflicts).
// No register prefetch, acc = 32 floats -> bounded VGPR (round-2 spill post-mortem).
template<int MODE>
__device__ __forceinline__ void gemm_tile(
    const float* __restrict__ X, int K,
    const float* __restrict__ W, const float* __restrict__ brow,
    float a_t, const float* __restrict__ Hprev,
    float* Xs, float* Ws, const int* nids,
    float* __restrict__ OUT)
{
    int tid = threadIdx.x;
    int cq = tid & 31, rq = tid >> 5;
    float acc[8][4];
    #pragma unroll
    for (int i = 0; i < 8; i++){ acc[i][0]=0.f; acc[i][1]=0.f; acc[i][2]=0.f; acc[i][3]=0.f; }

    for (int k0 = 0; k0 < K; k0 += 32){
        #pragma unroll
        for (int j = 0; j < 2; j++){                 // stage X: 512 float4 slots
            int slot = j * 256 + tid;
            int c4 = slot >> 6, row = slot & 63;
            int nid = nids[row];
            float4 xv = make_float4(0.f, 0.f, 0.f, 0.f);
            if (nid >= 0) xv = *(const float4*)(X + (size_t)nid * K + k0 + c4 * 4);
            *(float4*)&Xs[c4 * XB + row * 4] = xv;
        }
        #pragma unroll
        for (int j = 0; j < 4; j++){                 // stage W: 1024 float4 slots
            int slot = j * 256 + tid;
            int kk = slot >> 5, col4 = slot & 31;
            *(float4*)&Ws[kk * 128 + col4 * 4] =
                *(const float4*)(W + (size_t)(k0 + kk) * NH + col4 * 4);
        }
        __syncthreads();
        #pragma unroll 2
        for (int c4 = 0; c4 < 8; c4++){
            float4 w0 = *(const float4*)&Ws[(c4*4+0)*128 + cq*4];
            float4 w1 = *(const float4*)&Ws[(c4*4+1)*128 + cq*4];
            float4 w2 = *(const float4*)&Ws[(c4*4+2)*128 + cq*4];
            float4 w3 = *(const float4*)&Ws[(c4*4+3)*128 + cq*4];
            #pragma unroll
            for (int i = 0; i < 8; i++){
                float4 xv = *(const float4*)&Xs[c4 * XB + (rq + 8*i) * 4];
                acc[i][0] += xv.x*w0.x + xv.y*w1.x + xv.z*w2.x + xv.w*w3.x;
                acc[i][1] += xv.x*w0.y + xv.y*w1.y + xv.z*w2.y + xv.w*w3.y;
                acc[i][2] += xv.x*w0.z + xv.y*w1.z + xv.z*w2.z + xv.w*w3.z;
                acc[i][3] += xv.x*w0.w + xv.y*w1.w + xv.z*w2.w + xv.w*w3.w;
            }
        }
        __syncthreads();
    }

    float4 b4 = *(const float4*)(brow + cq * 4);
    float one_m = 1.f - a_t;
    #pragma unroll
    for (int i = 0; i < 8; i++){
        int r = rq + 8*i;
        int nid = nids[r];
        if (nid < 0) continue;
        float v0 = acc[i][0] + b4.x, v1 = acc[i][1] + b4.y;
        float v2 = acc[i][2] + b4.z, v3 = acc[i][3] + b4.w;
        if (MODE == 0){ v0 = gelu_f(v0); v1 = gelu_f(v1); v2 = gelu_f(v2); v3 = gelu_f(v3); }
        if (MODE == 2){
            float4 hp = *(const float4*)(Hprev + (size_t)nid * NH + cq * 4);
            v0 = v0 * a_t + hp.x * one_m; v1 = v1 * a_t + hp.y * one_m;
            v2 = v2 * a_t + hp.z * one_m; v3 = v3 * a_t + hp.w * one_m;
        }
        *(float4*)(OUT + (size_t)nid * NH + cq * 4) = make_float4(v0, v1, v2, v3);
    }
}

// ------------- per-type tiled GEMM: OUT[n,:] = epilogue( X[n,:] @ W[type(n)] + b[type(n)] )
// MODE 0: gelu(.)   MODE 1: identity   MODE 2: (.)*sig(skip[t]) + Hprev*(1-sig(skip[t]))
template<int MODE>
__global__ __launch_bounds__(256) void GNN_ptype_gemm(
    const float* __restrict__ X, int K,
    const float* __restrict__ Wall, const float* __restrict__ ball,
    const float* __restrict__ skiprow, const float* __restrict__ Hprev,
    const int* __restrict__ nperm, const int* __restrict__ counts,
    float* __restrict__ OUT)
{
    int t = blockIdx.y;
    int cnt = counts[t];
    int rbase = blockIdx.x * BN;
    if (rbase >= cnt) return;
    __shared__ float Xs[8 * XB];
    __shared__ float Ws[32 * 128];
    __shared__ int nids[BN];
    int tid = threadIdx.x;
    if (tid < BN){
        int idx = rbase + tid;
        nids[tid] = (idx < cnt) ? nperm[t * NN + idx] : -1;
    }
    __syncthreads();
    float a_t = 0.f;
    if (MODE == 2) a_t = 1.f / (1.f + expf(-skiprow[t]));
    gemm_tile<MODE>(X, K, Wall + (size_t)t * K * NH, ball + t * NH,
                    a_t, Hprev, Xs, Ws, nids, OUT);
}

// ------------- fused Q/K/V projections: blockIdx.z selects which (3x occupancy) ---------
__global__ __launch_bounds__(256) void GNN_qkv_gemm(
    const float* __restrict__ X,
    const float* __restrict__ Wq, const float* __restrict__ bq,
    const float* __restrict__ Wk, const float* __restrict__ bk,
    const float* __restrict__ Wv, const float* __restrict__ bv,
    const int* __restrict__ nperm, const int* __restrict__ counts,
    float* __restrict__ Qn, float* __restrict__ Kn, float* __restrict__ Vn)
{
    int t = blockIdx.y;
    int cnt = counts[t];
    int rbase = blockIdx.x * BN;
    if (rbase >= cnt) return;
    __shared__ float Xs[8 * XB];
    __shared__ float Ws[32 * 128];
    __shared__ int nids[BN];
    int tid = threadIdx.x;
    if (tid < BN){
        int idx = rbase + tid;
        nids[tid] = (idx < cnt) ? nperm[t * NN + idx] : -1;
    }
    __syncthreads();
    int z = blockIdx.z;
    const float* W = (z == 0) ? Wq : (z == 1) ? Wk : Wv;
    const float* b = (z == 0) ? bq : (z == 1) ? bk : bv;
    float* OUT     = (z == 0) ? Qn : (z == 1) ? Kn : Vn;
    gemm_tile<1>(X, NH, W + (size_t)t * NH * NH, b + t * NH,
                 0.f, nullptr, Xs, Ws, nids, OUT);
}

// ------------- RTE tables ----------------
__global__ void GNN_rte_tab(const float* __restrict__ rte_emb, const float* __restrict__ rW,
                            const float* __restrict__ rb, float* __restrict__ tab){
    int m = blockIdx.x, j = threadIdx.x;
    __shared__ float e[NH];
    e[j] = rte_emb[m * NH + j];
    __syncthreads();
    float a = rb[j];
    #pragma unroll 8
    for (int d = 0; d < NH; d++) a += e[d] * rW[d * NH + j];
    tab[m * NH + j] = a;
}

__global__ void GNN_rte_proj(const float* __restrict__ tab, const float* __restrict__ WkL,
                             const float* __restrict__ WvL, float* __restrict__ RK,
                             float* __restrict__ RV){
    int m = blockIdx.x, j = threadIdx.x;
    int sel = blockIdx.y; int t = sel >> 1; int which = sel & 1;
    const float* W = (which ? WvL : WkL) + (size_t)t * NH * NH;
    float* O = which ? RV : RK;
    __shared__ float e[NH];
    e[j] = tab[m * NH + j];
    __syncthreads();
    float a = 0.f;
    #pragma unroll 8
    for (int d = 0; d < NH; d++) a += e[d] * W[d * NH + j];
    O[(size_t)(t * 240 + m) * NH + j] = a;
}

// ------------- QA[r][i][h*32+d] = sum_c rel_att[r][h][d][c] * q[i][h*32+c] -----------
// Conflict-free LDS layouts:
//   Qs word index = row*144 + h*36 + c
//   Atp word index = h*1072 + nq*132 + c*4 + j  == A[h][d=nq*4+j][c]
__global__ __launch_bounds__(256) void GNN_qa(
    const float* __restrict__ Qn, const float* __restrict__ relA, float* __restrict__ QA)
{
    __shared__ float Atp[4 * 1072];        // 17152 B
    __shared__ float Qs[64 * 144];         // 36864 B
    int r = blockIdx.y;
    int nb = blockIdx.x * 64;
    int tid = threadIdx.x;
    const float* Ar = relA + (size_t)r * NHEAD * DK * DK;
    for (int x = tid; x < NHEAD * DK * DK; x += 256){
        int hh = x >> 10, rem = x & 1023, dd = rem >> 5, cc = rem & 31;
        Atp[hh * 1072 + (dd >> 2) * 132 + cc * 4 + (dd & 3)] = Ar[x];
    }
    for (int x = tid; x < 64 * 32; x += 256){
        int row = x >> 5, c4w = (x & 31) * 4;
        int hh = c4w >> 5, cc = c4w & 31;
        int node = nb + row;
        float4 qv = make_float4(0.f, 0.f, 0.f, 0.f);
        if (node < NN) qv = *(const float4*)(Qn + (size_t)node * NH + c4w);
        *(float4*)&Qs[row * 144 + hh * 36 + cc] = qv;
    }
    __syncthreads();
    int cq = tid & 31, rq = tid >> 5;
    int h = cq >> 3;
    int abase = h * 1072 + (cq & 7) * 132;
    int qbase = h * 36;
    float acc[8][4];
    #pragma unroll
    for (int i = 0; i < 8; i++){ acc[i][0]=0.f; acc[i][1]=0.f; acc[i][2]=0.f; acc[i][3]=0.f; }
    #pragma unroll 2
    for (int c4 = 0; c4 < 8; c4++){
        float4 av0 = *(const float4*)&Atp[abase + c4 * 16 + 0];
        float4 av1 = *(const float4*)&Atp[abase + c4 * 16 + 4];
        float4 av2 = *(const float4*)&Atp[abase + c4 * 16 + 8];
        float4 av3 = *(const float4*)&Atp[abase + c4 * 16 + 12];
        #pragma unroll
        for (int i = 0; i < 8; i++){
            float4 qv = *(const float4*)&Qs[(rq + 8*i) * 144 + qbase + c4 * 4];
            acc[i][0] += qv.x*av0.x + qv.y*av1.x + qv.z*av2.x + qv.w*av3.x;
            acc[i][1] += qv.x*av0.y + qv.y*av1.y + qv.z*av2.y + qv.w*av3.y;
            acc[i][2] += qv.x*av0.z + qv.y*av1.z + qv.z*av2.z + qv.w*av3.z;
            acc[i][3] += qv.x*av0.w + qv.y*av1.w + qv.z*av2.w + qv.w*av3.w;
        }
    }
    #pragma unroll
    for (int i = 0; i < 8; i++){
        int node = nb + rq + 8*i;
        if (node >= NN) continue;
        *(float4*)(QA + ((size_t)r * NN + node) * NH + cq * 4) =
            make_float4(acc[i][0], acc[i][1], acc[i][2], acc[i][3]);
    }
}

// ------------- E1: att[e,h] = (Kn[src]+RK[st,tm]) . QA[r][dst]  (32 lanes/edge, no LDS) ----
__global__ __launch_bounds__(256) void GNN_edge_att(
    const float* __restrict__ Kn, const float* __restrict__ RK, const float* __restrict__ QA,
    const int* __restrict__ esrc, const int* __restrict__ edst,
    const int* __restrict__ etype, const int* __restrict__ etime,
    const int* __restrict__ ntype, const float* __restrict__ relP,
    float* __restrict__ att)
{
    int tid = threadIdx.x;
    int e = blockIdx.x * 8 + (tid >> 5);
    if (e >= NE) return;
    int lane = tid & 31;
    int s = esrc[e], d = edst[e], r = etype[e], tm = etime[e];
    int st = ntype[s];
    float4 k4 = *(const float4*)(Kn + (size_t)s * NH + lane * 4);
    float4 rk = *(const float4*)(RK + (size_t)(st * 240 + tm) * NH + lane * 4);
    float4 qa = *(const float4*)(QA + ((size_t)r * NN + d) * NH + lane * 4);
    float pv = (k4.x + rk.x) * qa.x + (k4.y + rk.y) * qa.y
             + (k4.z + rk.z) * qa.z + (k4.w + rk.w) * qa.w;
    pv += __shfl_xor(pv, 4);
    pv += __shfl_xor(pv, 2);
    pv += __shfl_xor(pv, 1);
    if ((lane & 7) == 0){
        int head = lane >> 3;
        att[(size_t)e * NHEAD + head] = pv * relP[r * NHEAD + head] * RSQRT_DK;
    }
}

// ------------- E2a: per-node softmax + per-relation aggregation of raw v (no atomics) -----
__global__ __launch_bounds__(256) void GNN_node_aggr(
    const float* __restrict__ att, const float* __restrict__ Vn, const float* __restrict__ RV,
    const int* __restrict__ rowptr, const int* __restrict__ csr_e,
    const int* __restrict__ esrc, const int* __restrict__ etype,
    const int* __restrict__ etime, const int* __restrict__ ntype,
    float* __restrict__ P)
{
    int tid = threadIdx.x;
    int i = blockIdx.x * 8 + (tid >> 5);
    if (i >= NN) return;
    int lane = tid & 31;
    int head = lane >> 3;
    int beg = rowptr[i], end = rowptr[i + 1];
    // pass 1: segment max (all 8 lanes of a head read the same att value)
    float mx = -3.4e38f;
    for (int k = beg; k < end; k++){
        int e = csr_e[k];
        mx = fmaxf(mx, att[(size_t)e * NHEAD + head]);
    }
    // pass 2: accumulate exp-weighted raw v per relation, in registers
    float4 acc[NREL];
    #pragma unroll
    for (int rr = 0; rr < NREL; rr++) acc[rr] = make_float4(0.f, 0.f, 0.f, 0.f);
    float den = 0.f;
    for (int k = beg; k < end; k++){
        int e = csr_e[k];
        int s = esrc[e], r = etype[e], tm = etime[e];
        int st = ntype[s];
        float ex = expf(att[(size_t)e * NHEAD + head] - mx);
        den += ex;
        float4 v4 = *(const float4*)(Vn + (size_t)s * NH + lane * 4);
        float4 rv = *(const float4*)(RV + (size_t)(st * 240 + tm) * NH + lane * 4);
        float vx = v4.x + rv.x, vy = v4.y + rv.y, vz = v4.z + rv.z, vw = v4.w + rv.w;
        #pragma unroll
        for (int rr = 0; rr < NREL; rr++){
            float w = (rr == r) ? ex : 0.f;     // predicated, keeps acc in registers
            acc[rr].x += w * vx; acc[rr].y += w * vy;
            acc[rr].z += w * vz; acc[rr].w += w * vw;
        }
    }
    float inv = 1.f / (den + 1e-16f);
    #pragma unroll
    for (int rr = 0; rr < NREL; rr++){
        *(float4*)(P + ((size_t)rr * NN + i) * NH + lane * 4) =
            make_float4(acc[rr].x * inv, acc[rr].y * inv, acc[rr].z * inv, acc[rr].w * inv);
    }
}

// ------------- E2b: aggr[i][h*32+c] = gelu( sum_r sum_d P[r][i][h*32+d] * M_r[h][d][c] ) ---
//   Msp[h*1072 + nq*132 + d*4 + j] = M[h][d][c = nq*4+j]
__global__ __launch_bounds__(256) void GNN_pm(
    const float* __restrict__ P, const float* __restrict__ relM, float* __restrict__ aggr)
{
    __shared__ float Msp[4 * 1072];
    __shared__ float Ps[64 * 144];
    int tid = threadIdx.x;
    int nb = blockIdx.x * 64;
    int cq = tid & 31, rq = tid >> 5;
    int h = cq >> 3;
    int mbase = h * 1072 + (cq & 7) * 132;
    int pbase = h * 36;
    float acc[8][4];
    #pragma unroll
    for (int i = 0; i < 8; i++){ acc[i][0]=0.f; acc[i][1]=0.f; acc[i][2]=0.f; acc[i][3]=0.f; }
    for (int r = 0; r < NREL; r++){
        const float* Mr = relM + (size_t)r * NHEAD * DK * DK;
        for (int x = tid; x < NHEAD * DK * DK; x += 256){
            int hh = x >> 10, rem = x & 1023, dd = rem >> 5, kk = rem & 31;
            Msp[hh * 1072 + (kk >> 2) * 132 + dd * 4 + (kk & 3)] = Mr[x];
        }
        for (int x = tid; x < 64 * 32; x += 256){
            int row = x >> 5, c4w = (x & 31) * 4;
            int hh = c4w >> 5, cc = c4w & 31;
            int node = nb + row;
            float4 pv = make_float4(0.f, 0.f, 0.f, 0.f);
            if (node < NN) pv = *(const float4*)(P + ((size_t)r * NN + node) * NH + c4w);
            *(float4*)&Ps[row * 144 + hh * 36 + cc] = pv;
        }
        __syncthreads();
        #pragma unroll 2
        for (int d4 = 0; d4 < 8; d4++){
            float4 mv0 = *(const float4*)&Msp[mbase + d4 * 16 + 0];
            float4 mv1 = *(const float4*)&Msp[mbase + d4 * 16 + 4];
            float4 mv2 = *(const float4*)&Msp[mbase + d4 * 16 + 8];
            float4 mv3 = *(const float4*)&Msp[mbase + d4 * 16 + 12];
            #pragma unroll
            for (int i = 0; i < 8; i++){
                float4 pv = *(const float4*)&Ps[(rq + 8*i) * 144 + pbase + d4 * 4];
                acc[i][0] += pv.x*mv0.x + pv.y*mv1.x + pv.z*mv2.x + pv.w*mv3.x;
                acc[i][1] += pv.x*mv0.y + pv.y*mv1.y + pv.z*mv2.y + pv.w*mv3.y;
                acc[i][2] += pv.x*mv0.z + pv.y*mv1.z + pv.z*mv2.z + pv.w*mv3.z;
                acc[i][3] += pv.x*mv0.w + pv.y*mv1.w + pv.z*mv2.w + pv.w*mv3.w;
            }
        }
        __syncthreads();
    }
    #pragma unroll
    for (int i = 0; i < 8; i++){
        int node = nb + rq + 8*i;
        if (node >= NN) continue;
        *(float4*)(aggr + (size_t)node * NH + cq * 4) =
            make_float4(gelu_f(acc[i][0]), gelu_f(acc[i][1]),
                        gelu_f(acc[i][2]), gelu_f(acc[i][3]));
    }
}

extern "C" void kernel_launch(void* const* d_in, const int* in_sizes, int n_in,
                              void* d_out, int out_size, void* d_ws, size_t ws_size,
                              hipStream_t stream)
{
    const float* node_feature = (const float*)d_in[0];
    const float* adapt_W = (const float*)d_in[1];
    const float* adapt_b = (const float*)d_in[2];
    const float* Wk = (const float*)d_in[3];
    const float* bk = (const float*)d_in[4];
    const float* Wq = (const float*)d_in[5];
    const float* bq = (const float*)d_in[6];
    const float* Wv = (const float*)d_in[7];
    const float* bv = (const float*)d_in[8];
    const float* Wa = (const float*)d_in[9];
    const float* ba = (const float*)d_in[10];
    const float* rel_pri = (const float*)d_in[11];
    const float* rel_att = (const float*)d_in[12];
    const float* rel_msg = (const float*)d_in[13];
    const float* skip = (const float*)d_in[14];
    const float* rte_emb = (const float*)d_in[15];
    const float* rte_W = (const float*)d_in[16];
    const float* rte_b = (const float*)d_in[17];
    const int* node_type = (const int*)d_in[18];
    const int* edge_index = (const int*)d_in[19];
    const int* edge_type = (const int*)d_in[20];
    const int* edge_time = (const int*)d_in[21];
    const int* esrc = edge_index;          // row 0 = source j
    const int* edst = edge_index + NE;     // row 1 = target i

    char* p = (char*)d_ws;
    auto alloc = [&](size_t bytes) -> char* {
        char* r = p; p += (bytes + 255) & ~(size_t)255; return r;
    };
    float* hA    = (float*)alloc((size_t)NN * NH * 4);
    float* Qn    = (float*)alloc((size_t)NN * NH * 4);      // att aliases this (E1..E2a window)
    float* Kn    = (float*)alloc((size_t)NN * NH * 4);      // aggr aliases this (E2b..Wa window)
    float* Vn    = (float*)alloc((size_t)NN * NH * 4);
    float* QA    = (float*)alloc((size_t)NREL * NN * NH * 4);  // P aliases this (E2a..E2b)
    float* rtab  = (float*)alloc((size_t)240 * NH * 4);
    float* RK    = (float*)alloc((size_t)NTYPE * 240 * NH * 4);
    float* RV    = (float*)alloc((size_t)NTYPE * 240 * NH * 4);
    int* nperm   = (int*)alloc((size_t)NTYPE * NN * 4);
    int* rowptr  = (int*)alloc((size_t)(NN + 1) * 4);
    int* csr_e   = (int*)alloc((size_t)NE * 4);
    int* deg     = (int*)alloc((size_t)2 * NN * 4);   // deg+cursor in ONE block: the single
    int* cursor  = deg + NN;                          // memset covers both exactly
    int* bsum    = (int*)alloc(256 * 4);
    int* bbase   = (int*)alloc(256 * 4);
    int* ncur    = (int*)alloc(64);
    float* att   = Qn;      // [NE*NHEAD] = 6.4 MB < 25.6 MB
    float* Pbuf  = QA;      // per-(relation,node) aggregate
    float* aggr  = Kn;

    hipMemsetAsync(ncur, 0, 64, stream);
    hipMemsetAsync(deg, 0, (size_t)2 * NN * 4, stream);     // covers deg AND cursor exactly

    GNN_nscatter<<<(NN + 255) / 256, 256, 0, stream>>>(node_type, ncur, nperm);
    GNN_deg<<<(NE + 255) / 256, 256, 0, stream>>>(edst, deg);
    GNN_scan1<<<NSCAN_BLK, 256, 0, stream>>>(deg, rowptr, bsum);
    GNN_scan2<<<1, 256, 0, stream>>>(bsum, bbase);
    GNN_scan3<<<NSCAN_BLK, 256, 0, stream>>>(rowptr, bbase);
    GNN_csr_scatter<<<(NE + 255) / 256, 256, 0, stream>>>(edst, rowptr, cursor, csr_e);

    dim3 ggrid((NN + BN - 1) / BN, NTYPE);
    GNN_ptype_gemm<0><<<ggrid, 256, 0, stream>>>(node_feature, INDIM, adapt_W, adapt_b,
                                                 nullptr, nullptr, nperm, ncur, hA);
    const float* hin = hA;
    for (int l = 0; l < 2; l++){
        const float* WkL = Wk + (size_t)l * NTYPE * NH * NH;
        const float* WqL = Wq + (size_t)l * NTYPE * NH * NH;
        const float* WvL = Wv + (size_t)l * NTYPE * NH * NH;
        const float* WaL = Wa + (size_t)l * NTYPE * NH * NH;
        const float* bkL = bk + (size_t)l * NTYPE * NH;
        const float* bqL = bq + (size_t)l * NTYPE * NH;
        const float* bvL = bv + (size_t)l * NTYPE * NH;
        const float* baL = ba + (size_t)l * NTYPE * NH;
        const float* relA = rel_att + (size_t)l * NREL * NHEAD * DK * DK;
        const float* relM = rel_msg + (size_t)l * NREL * NHEAD * DK * DK;
        const float* relP = rel_pri + (size_t)l * NREL * NHEAD;

        GNN_rte_tab<<<240, 128, 0, stream>>>(rte_emb, rte_W + (size_t)l * NH * NH,
                                             rte_b + (size_t)l * NH, rtab);
        GNN_rte_proj<<<dim3(240, NTYPE * 2), 128, 0, stream>>>(rtab, WkL, WvL, RK, RV);

        GNN_qkv_gemm<<<dim3(ggrid.x, NTYPE, 3), 256, 0, stream>>>(
            hin, WqL, bqL, WkL, bkL, WvL, bvL, nperm, ncur, Qn, Kn, Vn);

        GNN_qa<<<dim3((NN + 63) / 64, NREL), 256, 0, stream>>>(Qn, relA, QA);

        GNN_edge_att<<<(NE + 7) / 8, 256, 0, stream>>>(
            Kn, RK, QA, esrc, edst, edge_type, edge_time, node_type, relP, att);

        GNN_node_aggr<<<(NN + 7) / 8, 256, 0, stream>>>(
            att, Vn, RV, rowptr, csr_e, esrc, edge_type, edge_time, node_type, Pbuf);

        GNN_pm<<<(NN + 63) / 64, 256, 0, stream>>>(Pbuf, relM, aggr);

        float* hout = (l == 0) ? hA : (float*)d_out;   // l==0 in-place on hA is safe:
        GNN_ptype_gemm<2><<<ggrid, 256, 0, stream>>>(  // epilogue reads Hprev[nid,cols] then
            aggr, NH, WaL, baL, skip + (size_t)l * NTYPE, hin,   // writes same elems, same thread
            nperm, ncur, hout);
        hin = hout;
    }
}

// Round 4
// 1133.256 us; speedup vs baseline: 2.9863x; 1.0198x over previous
//
#include <hip/hip_runtime.h>
#include <math.h>

// ---- problem constants ----
#define NN     50000
#define NE     400000
#define INDIM  256
#define NH     128
#define NTYPE  4
#define NREL   5
#define NHEAD  4
#define DK     32
#define RSQRT_DK 0.17677669529663687f
#define BN     64
#define NSCAN_BLK ((NN + 255) / 256)   // 196
#define XB     260                     // Xs c4-block stride in words (260*4B, 16B-aligned)

__device__ __forceinline__ float gelu_f(float x){
    return 0.5f * x * (1.0f + erff(x * 0.70710678118654752f));
}

// ---------------- node bucketing by type (for per-type GEMMs) ----------------
__global__ void GNN_nscatter(const int* __restrict__ ntype, int* __restrict__ ncur,
                             int* __restrict__ nperm){
    __shared__ int lcnt[4], lbase[4];
    int tid = threadIdx.x;
    if (tid < 4) lcnt[tid] = 0;
    __syncthreads();
    int n = blockIdx.x * 256 + tid;
    int t = 0, lpos = 0;
    bool ok = (n < NN);
    if (ok){ t = ntype[n]; lpos = atomicAdd(&lcnt[t], 1); }
    __syncthreads();
    if (tid < 4 && lcnt[tid] > 0) lbase[tid] = atomicAdd(&ncur[tid], lcnt[tid]);
    __syncthreads();
    if (ok) nperm[t * NN + lbase[t] + lpos] = n;
}

// ---------------- CSR by destination (built once per call) ----------------
__global__ void GNN_deg(const int* __restrict__ edst, int* __restrict__ deg){
    int e = blockIdx.x * 256 + threadIdx.x;
    if (e < NE) atomicAdd(&deg[edst[e]], 1);
}

__global__ void GNN_scan1(const int* __restrict__ deg, int* __restrict__ rowptr,
                          int* __restrict__ bsum){
    __shared__ int s[256];
    int g = blockIdx.x * 256 + threadIdx.x;
    int v = (g < NN) ? deg[g] : 0;
    s[threadIdx.x] = v;
    __syncthreads();
    for (int off = 1; off < 256; off <<= 1){
        int t = (threadIdx.x >= off) ? s[threadIdx.x - off] : 0;
        __syncthreads();
        s[threadIdx.x] += t;
        __syncthreads();
    }
    if (g < NN) rowptr[g] = s[threadIdx.x] - v;           // block-local exclusive
    if (threadIdx.x == 255) bsum[blockIdx.x] = s[255];
}

__global__ void GNN_scan2(const int* __restrict__ bsum, int* __restrict__ bbase){
    __shared__ int s[256];
    int v = (threadIdx.x < NSCAN_BLK) ? bsum[threadIdx.x] : 0;
    s[threadIdx.x] = v;
    __syncthreads();
    for (int off = 1; off < 256; off <<= 1){
        int t = (threadIdx.x >= off) ? s[threadIdx.x - off] : 0;
        __syncthreads();
        s[threadIdx.x] += t;
        __syncthreads();
    }
    bbase[threadIdx.x] = s[threadIdx.x] - v;              // exclusive
}

__global__ void GNN_scan3(int* __restrict__ rowptr, const int* __restrict__ bbase){
    int g = blockIdx.x * 256 + threadIdx.x;
    if (g < NN) rowptr[g] += bbase[blockIdx.x];
    if (g == 0) rowptr[NN] = NE;
}

__global__ void GNN_csr_scatter(const int* __restrict__ edst, const int* __restrict__ rowptr,
                                int* __restrict__ cursor, int* __restrict__ csr_e){
    int e = blockIdx.x * 256 + threadIdx.x;
    if (e >= NE) return;
    int d = edst[e];
    int pos = atomicAdd(&cursor[d], 1);
    csr_e[rowptr[d] + pos] = e;
}

// ------------- shared GEMM tile core: 256 threads, 64 rows x 128 cols, 8x4 per thread.
// Xs layout: c4-block-major, word = c4*XB + row*4.  Ws: [32][128] contiguous.
// No register prefetch, acc = 32 floats -> bounded VGPR (round-2 spill post-mortem).
template<int MODE>
__device__ __forceinline__ void gemm_tile(
    const float* __restrict__ X, int K,
    const float* __restrict__ W, const float* __restrict__ brow,
    float a_t, const float* __restrict__ Hprev,
    float* Xs, float* Ws, const int* nids,
    float* __restrict__ OUT)
{
    int tid = threadIdx.x;
    int cq = tid & 31, rq = tid >> 5;
    float acc[8][4];
    #pragma unroll
    for (int i = 0; i < 8; i++){ acc[i][0]=0.f; acc[i][1]=0.f; acc[i][2]=0.f; acc[i][3]=0.f; }

    for (int k0 = 0; k0 < K; k0 += 32){
        #pragma unroll
        for (int j = 0; j < 2; j++){                 // stage X: 512 float4 slots
            int slot = j * 256 + tid;
            int c4 = slot >> 6, row = slot & 63;
            int nid = nids[row];
            float4 xv = make_float4(0.f, 0.f, 0.f, 0.f);
            if (nid >= 0) xv = *(const float4*)(X + (size_t)nid * K + k0 + c4 * 4);
            *(float4*)&Xs[c4 * XB + row * 4] = xv;
        }
        #pragma unroll
        for (int j = 0; j < 4; j++){                 // stage W: 1024 float4 slots
            int slot = j * 256 + tid;
            int kk = slot >> 5, col4 = slot & 31;
            *(float4*)&Ws[kk * 128 + col4 * 4] =
                *(const float4*)(W + (size_t)(k0 + kk) * NH + col4 * 4);
        }
        __syncthreads();
        #pragma unroll 2
        for (int c4 = 0; c4 < 8; c4++){
            float4 w0 = *(const float4*)&Ws[(c4*4+0)*128 + cq*4];
            float4 w1 = *(const float4*)&Ws[(c4*4+1)*128 + cq*4];
            float4 w2 = *(const float4*)&Ws[(c4*4+2)*128 + cq*4];
            float4 w3 = *(const float4*)&Ws[(c4*4+3)*128 + cq*4];
            #pragma unroll
            for (int i = 0; i < 8; i++){
                float4 xv = *(const float4*)&Xs[c4 * XB + (rq + 8*i) * 4];
                acc[i][0] += xv.x*w0.x + xv.y*w1.x + xv.z*w2.x + xv.w*w3.x;
                acc[i][1] += xv.x*w0.y + xv.y*w1.y + xv.z*w2.y + xv.w*w3.y;
                acc[i][2] += xv.x*w0.z + xv.y*w1.z + xv.z*w2.z + xv.w*w3.z;
                acc[i][3] += xv.x*w0.w + xv.y*w1.w + xv.z*w2.w + xv.w*w3.w;
            }
        }
        __syncthreads();
    }

    float4 b4 = *(const float4*)(brow + cq * 4);
    float one_m = 1.f - a_t;
    #pragma unroll
    for (int i = 0; i < 8; i++){
        int r = rq + 8*i;
        int nid = nids[r];
        if (nid < 0) continue;
        float v0 = acc[i][0] + b4.x, v1 = acc[i][1] + b4.y;
        float v2 = acc[i][2] + b4.z, v3 = acc[i][3] + b4.w;
        if (MODE == 0){ v0 = gelu_f(v0); v1 = gelu_f(v1); v2 = gelu_f(v2); v3 = gelu_f(v3); }
        if (MODE == 2){
            float4 hp = *(const float4*)(Hprev + (size_t)nid * NH + cq * 4);
            v0 = v0 * a_t + hp.x * one_m; v1 = v1 * a_t + hp.y * one_m;
            v2 = v2 * a_t + hp.z * one_m; v3 = v3 * a_t + hp.w * one_m;
        }
        *(float4*)(OUT + (size_t)nid * NH + cq * 4) = make_float4(v0, v1, v2, v3);
    }
}

// ------------- per-type tiled GEMM: OUT[n,:] = epilogue( X[n,:] @ W[type(n)] + b[type(n)] )
// MODE 0: gelu(.)   MODE 1: identity   MODE 2: (.)*sig(skip[t]) + Hprev*(1-sig(skip[t]))
template<int MODE>
__global__ __launch_bounds__(256) void GNN_ptype_gemm(
    const float* __restrict__ X, int K,
    const float* __restrict__ Wall, const float* __restrict__ ball,
    const float* __restrict__ skiprow, const float* __restrict__ Hprev,
    const int* __restrict__ nperm, const int* __restrict__ counts,
    float* __restrict__ OUT)
{
    int t = blockIdx.y;
    int cnt = counts[t];
    int rbase = blockIdx.x * BN;
    if (rbase >= cnt) return;
    __shared__ float Xs[8 * XB];
    __shared__ float Ws[32 * 128];
    __shared__ int nids[BN];
    int tid = threadIdx.x;
    if (tid < BN){
        int idx = rbase + tid;
        nids[tid] = (idx < cnt) ? nperm[t * NN + idx] : -1;
    }
    __syncthreads();
    float a_t = 0.f;
    if (MODE == 2) a_t = 1.f / (1.f + expf(-skiprow[t]));
    gemm_tile<MODE>(X, K, Wall + (size_t)t * K * NH, ball + t * NH,
                    a_t, Hprev, Xs, Ws, nids, OUT);
}

// ------------- fused Q/K/V projections: blockIdx.z selects which (3x occupancy) ---------
__global__ __launch_bounds__(256) void GNN_qkv_gemm(
    const float* __restrict__ X,
    const float* __restrict__ Wq, const float* __restrict__ bq,
    const float* __restrict__ Wk, const float* __restrict__ bk,
    const float* __restrict__ Wv, const float* __restrict__ bv,
    const int* __restrict__ nperm, const int* __restrict__ counts,
    float* __restrict__ Qn, float* __restrict__ Kn, float* __restrict__ Vn)
{
    int t = blockIdx.y;
    int cnt = counts[t];
    int rbase = blockIdx.x * BN;
    if (rbase >= cnt) return;
    __shared__ float Xs[8 * XB];
    __shared__ float Ws[32 * 128];
    __shared__ int nids[BN];
    int tid = threadIdx.x;
    if (tid < BN){
        int idx = rbase + tid;
        nids[tid] = (idx < cnt) ? nperm[t * NN + idx] : -1;
    }
    __syncthreads();
    int z = blockIdx.z;
    const float* W = (z == 0) ? Wq : (z == 1) ? Wk : Wv;
    const float* b = (z == 0) ? bq : (z == 1) ? bk : bv;
    float* OUT     = (z == 0) ? Qn : (z == 1) ? Kn : Vn;
    gemm_tile<1>(X, NH, W + (size_t)t * NH * NH, b + t * NH,
                 0.f, nullptr, Xs, Ws, nids, OUT);
}

// ------------- RTE tables ----------------
__global__ void GNN_rte_tab(const float* __restrict__ rte_emb, const float* __restrict__ rW,
                            const float* __restrict__ rb, float* __restrict__ tab){
    int m = blockIdx.x, j = threadIdx.x;
    __shared__ float e[NH];
    e[j] = rte_emb[m * NH + j];
    __syncthreads();
    float a = rb[j];
    #pragma unroll 8
    for (int d = 0; d < NH; d++) a += e[d] * rW[d * NH + j];
    tab[m * NH + j] = a;
}

__global__ void GNN_rte_proj(const float* __restrict__ tab, const float* __restrict__ WkL,
                             const float* __restrict__ WvL, float* __restrict__ RK,
                             float* __restrict__ RV){
    int m = blockIdx.x, j = threadIdx.x;
    int sel = blockIdx.y; int t = sel >> 1; int which = sel & 1;
    const float* W = (which ? WvL : WkL) + (size_t)t * NH * NH;
    float* O = which ? RV : RK;
    __shared__ float e[NH];
    e[j] = tab[m * NH + j];
    __syncthreads();
    float a = 0.f;
    #pragma unroll 8
    for (int d = 0; d < NH; d++) a += e[d] * W[d * NH + j];
    O[(size_t)(t * 240 + m) * NH + j] = a;
}

// ------------- QA[r][i][h*32+d] = sum_c rel_att[r][h][d][c] * q[i][h*32+c] -----------
// v2: no Q LDS tile — Q read as 8-lane-broadcast float4 from global inside the FMA loop
// (address independent of q=cq&7). Atp stays in LDS (17 KB), ONE barrier per block.
//   Atp word index = h*1072 + (d>>2)*132 + c*4 + (d&3)
__global__ __launch_bounds__(256) void GNN_qa(
    const float* __restrict__ Qn, const float* __restrict__ relA, float* __restrict__ QA)
{
    __shared__ float Atp[4 * 1072];        // 17152 B
    int r = blockIdx.y;
    int nb = blockIdx.x * 64;
    int tid = threadIdx.x;
    const float* Ar = relA + (size_t)r * NHEAD * DK * DK;
    for (int x = tid; x < NHEAD * DK * DK; x += 256){
        int hh = x >> 10, rem = x & 1023, dd = rem >> 5, cc = rem & 31;
        Atp[hh * 1072 + (dd >> 2) * 132 + cc * 4 + (dd & 3)] = Ar[x];
    }
    __syncthreads();
    int cq = tid & 31, rq = tid >> 5;
    int h = cq >> 3;
    int abase = h * 1072 + (cq & 7) * 132;
    int rowoff[8];
    #pragma unroll
    for (int i = 0; i < 8; i++){
        int node = nb + rq + 8*i;
        if (node >= NN) node = NN - 1;              // clamp: write is guarded below
        rowoff[i] = node * NH + h * 32;
    }
    float acc[8][4];
    #pragma unroll
    for (int i = 0; i < 8; i++){ acc[i][0]=0.f; acc[i][1]=0.f; acc[i][2]=0.f; acc[i][3]=0.f; }
    #pragma unroll 2
    for (int c4 = 0; c4 < 8; c4++){
        float4 av0 = *(const float4*)&Atp[abase + c4 * 16 + 0];
        float4 av1 = *(const float4*)&Atp[abase + c4 * 16 + 4];
        float4 av2 = *(const float4*)&Atp[abase + c4 * 16 + 8];
        float4 av3 = *(const float4*)&Atp[abase + c4 * 16 + 12];
        #pragma unroll
        for (int i = 0; i < 8; i++){
            float4 qv = *(const float4*)(Qn + rowoff[i] + c4 * 4);
            acc[i][0] += qv.x*av0.x + qv.y*av1.x + qv.z*av2.x + qv.w*av3.x;
            acc[i][1] += qv.x*av0.y + qv.y*av1.y + qv.z*av2.y + qv.w*av3.y;
            acc[i][2] += qv.x*av0.z + qv.y*av1.z + qv.z*av2.z + qv.w*av3.z;
            acc[i][3] += qv.x*av0.w + qv.y*av1.w + qv.z*av2.w + qv.w*av3.w;
        }
    }
    #pragma unroll
    for (int i = 0; i < 8; i++){
        int node = nb + rq + 8*i;
        if (node >= NN) continue;
        *(float4*)(QA + ((size_t)r * NN + node) * NH + cq * 4) =
            make_float4(acc[i][0], acc[i][1], acc[i][2], acc[i][3]);
    }
}

// ------------- E1: att[e,h] = (Kn[src]+RK[st,tm]) . QA[r][dst]  (32 lanes/edge, no LDS) ----
__global__ __launch_bounds__(256) void GNN_edge_att(
    const float* __restrict__ Kn, const float* __restrict__ RK, const float* __restrict__ QA,
    const int* __restrict__ esrc, const int* __restrict__ edst,
    const int* __restrict__ etype, const int* __restrict__ etime,
    const int* __restrict__ ntype, const float* __restrict__ relP,
    float* __restrict__ att)
{
    int tid = threadIdx.x;
    int e = blockIdx.x * 8 + (tid >> 5);
    if (e >= NE) return;
    int lane = tid & 31;
    int s = esrc[e], d = edst[e], r = etype[e], tm = etime[e];
    int st = ntype[s];
    float4 k4 = *(const float4*)(Kn + (size_t)s * NH + lane * 4);
    float4 rk = *(const float4*)(RK + (size_t)(st * 240 + tm) * NH + lane * 4);
    float4 qa = *(const float4*)(QA + ((size_t)r * NN + d) * NH + lane * 4);
    float pv = (k4.x + rk.x) * qa.x + (k4.y + rk.y) * qa.y
             + (k4.z + rk.z) * qa.z + (k4.w + rk.w) * qa.w;
    pv += __shfl_xor(pv, 4);
    pv += __shfl_xor(pv, 2);
    pv += __shfl_xor(pv, 1);
    if ((lane & 7) == 0){
        int head = lane >> 3;
        att[(size_t)e * NHEAD + head] = pv * relP[r * NHEAD + head] * RSQRT_DK;
    }
}

// ------------- E2a: per-node softmax + per-relation aggregation of raw v (no atomics) -----
__global__ __launch_bounds__(256) void GNN_node_aggr(
    const float* __restrict__ att, const float* __restrict__ Vn, const float* __restrict__ RV,
    const int* __restrict__ rowptr, const int* __restrict__ csr_e,
    const int* __restrict__ esrc, const int* __restrict__ etype,
    const int* __restrict__ etime, const int* __restrict__ ntype,
    float* __restrict__ P)
{
    int tid = threadIdx.x;
    int i = blockIdx.x * 8 + (tid >> 5);
    if (i >= NN) return;
    int lane = tid & 31;
    int head = lane >> 3;
    int beg = rowptr[i], end = rowptr[i + 1];
    // pass 1: segment max (all 8 lanes of a head read the same att value)
    float mx = -3.4e38f;
    for (int k = beg; k < end; k++){
        int e = csr_e[k];
        mx = fmaxf(mx, att[(size_t)e * NHEAD + head]);
    }
    // pass 2: accumulate exp-weighted raw v per relation, in registers
    float4 acc[NREL];
    #pragma unroll
    for (int rr = 0; rr < NREL; rr++) acc[rr] = make_float4(0.f, 0.f, 0.f, 0.f);
    float den = 0.f;
    for (int k = beg; k < end; k++){
        int e = csr_e[k];
        int s = esrc[e], r = etype[e], tm = etime[e];
        int st = ntype[s];
        float ex = expf(att[(size_t)e * NHEAD + head] - mx);
        den += ex;
        float4 v4 = *(const float4*)(Vn + (size_t)s * NH + lane * 4);
        float4 rv = *(const float4*)(RV + (size_t)(st * 240 + tm) * NH + lane * 4);
        float vx = v4.x + rv.x, vy = v4.y + rv.y, vz = v4.z + rv.z, vw = v4.w + rv.w;
        #pragma unroll
        for (int rr = 0; rr < NREL; rr++){
            float w = (rr == r) ? ex : 0.f;     // predicated, keeps acc in registers
            acc[rr].x += w * vx; acc[rr].y += w * vy;
            acc[rr].z += w * vz; acc[rr].w += w * vw;
        }
    }
    float inv = 1.f / (den + 1e-16f);
    #pragma unroll
    for (int rr = 0; rr < NREL; rr++){
        *(float4*)(P + ((size_t)rr * NN + i) * NH + lane * 4) =
            make_float4(acc[rr].x * inv, acc[rr].y * inv, acc[rr].z * inv, acc[rr].w * inv);
    }
}

// ------------- E2b: aggr[i][h*32+c] = gelu( sum_r sum_d P[r][i][h*32+d] * M_r[h][d][c] ) ---
// v2: no Ps LDS tile — P read as 8-lane-broadcast float4 from global in the FMA loop.
// Msp double-buffered in LDS with register prefetch of M(r+1) under compute of r (T14).
//   Msp word = h*1072 + (d>>2)*132 + ... stored transposed:
//   element M[hh][dd][kk] at word hh*1072 + (kk>>2)*132 + dd*4 + (kk&3).
//   Staging vectorizes: global float4 slot s covers kk = 4(s&7)+{0..3} at fixed
//   (hh = s>>8, dd = (s>>3)&31) -> dest words contiguous.
__global__ __launch_bounds__(256) void GNN_pm(
    const float* __restrict__ P, const float* __restrict__ relM, float* __restrict__ aggr)
{
    __shared__ float Msp[2][4 * 1072];     // 2 x 17152 B
    int tid = threadIdx.x;
    int nb = blockIdx.x * 64;
    int cq = tid & 31, rq = tid >> 5;
    int h = cq >> 3;
    int mbase = h * 1072 + (cq & 7) * 132;
    int rowoff[8];
    #pragma unroll
    for (int i = 0; i < 8; i++){
        int node = nb + rq + 8*i;
        if (node >= NN) node = NN - 1;              // clamp: write is guarded below
        rowoff[i] = node * NH + h * 32;
    }
    float acc[8][4];
    #pragma unroll
    for (int i = 0; i < 8; i++){ acc[i][0]=0.f; acc[i][1]=0.f; acc[i][2]=0.f; acc[i][3]=0.f; }

    // prologue: stage M(0) into buffer 0
    #pragma unroll
    for (int j = 0; j < 4; j++){
        int s = tid + 256 * j;
        float4 mv = *(const float4*)(relM + 4 * s);
        *(float4*)&Msp[0][(s >> 8) * 1072 + (s & 7) * 132 + ((s >> 3) & 31) * 4] = mv;
    }
    __syncthreads();

    #pragma unroll
    for (int r = 0; r < NREL; r++){
        float4 mpre[4];
        if (r + 1 < NREL){                           // prefetch next M under compute
            const float* Mn = relM + (size_t)(r + 1) * NHEAD * DK * DK;
            #pragma unroll
            for (int j = 0; j < 4; j++)
                mpre[j] = *(const float4*)(Mn + 4 * (tid + 256 * j));
        }
        const float* Ms = Msp[r & 1];
        const float* Pr = P + (size_t)r * NN * NH;
        #pragma unroll 2
        for (int d4 = 0; d4 < 8; d4++){
            float4 mv0 = *(const float4*)&Ms[mbase + d4 * 16 + 0];
            float4 mv1 = *(const float4*)&Ms[mbase + d4 * 16 + 4];
            float4 mv2 = *(const float4*)&Ms[mbase + d4 * 16 + 8];
            float4 mv3 = *(const float4*)&Ms[mbase + d4 * 16 + 12];
            #pragma unroll
            for (int i = 0; i < 8; i++){
                float4 pv = *(const float4*)(Pr + rowoff[i] + d4 * 4);
                acc[i][0] += pv.x*mv0.x + pv.y*mv1.x + pv.z*mv2.x + pv.w*mv3.x;
                acc[i][1] += pv.x*mv0.y + pv.y*mv1.y + pv.z*mv2.y + pv.w*mv3.y;
                acc[i][2] += pv.x*mv0.z + pv.y*mv1.z + pv.z*mv2.z + pv.w*mv3.z;
                acc[i][3] += pv.x*mv0.w + pv.y*mv1.w + pv.z*mv2.w + pv.w*mv3.w;
            }
        }
        if (r + 1 < NREL){
            #pragma unroll
            for (int j = 0; j < 4; j++){
                int s = tid + 256 * j;
                *(float4*)&Msp[(r + 1) & 1][(s >> 8) * 1072 + (s & 7) * 132 +
                                            ((s >> 3) & 31) * 4] = mpre[j];
            }
            __syncthreads();
        }
    }
    #pragma unroll
    for (int i = 0; i < 8; i++){
        int node = nb + rq + 8*i;
        if (node >= NN) continue;
        *(float4*)(aggr + (size_t)node * NH + cq * 4) =
            make_float4(gelu_f(acc[i][0]), gelu_f(acc[i][1]),
                        gelu_f(acc[i][2]), gelu_f(acc[i][3]));
    }
}

extern "C" void kernel_launch(void* const* d_in, const int* in_sizes, int n_in,
                              void* d_out, int out_size, void* d_ws, size_t ws_size,
                              hipStream_t stream)
{
    const float* node_feature = (const float*)d_in[0];
    const float* adapt_W = (const float*)d_in[1];
    const float* adapt_b = (const float*)d_in[2];
    const float* Wk = (const float*)d_in[3];
    const float* bk = (const float*)d_in[4];
    const float* Wq = (const float*)d_in[5];
    const float* bq = (const float*)d_in[6];
    const float* Wv = (const float*)d_in[7];
    const float* bv = (const float*)d_in[8];
    const float* Wa = (const float*)d_in[9];
    const float* ba = (const float*)d_in[10];
    const float* rel_pri = (const float*)d_in[11];
    const float* rel_att = (const float*)d_in[12];
    const float* rel_msg = (const float*)d_in[13];
    const float* skip = (const float*)d_in[14];
    const float* rte_emb = (const float*)d_in[15];
    const float* rte_W = (const float*)d_in[16];
    const float* rte_b = (const float*)d_in[17];
    const int* node_type = (const int*)d_in[18];
    const int* edge_index = (const int*)d_in[19];
    const int* edge_type = (const int*)d_in[20];
    const int* edge_time = (const int*)d_in[21];
    const int* esrc = edge_index;          // row 0 = source j
    const int* edst = edge_index + NE;     // row 1 = target i

    char* p = (char*)d_ws;
    auto alloc = [&](size_t bytes) -> char* {
        char* r = p; p += (bytes + 255) & ~(size_t)255; return r;
    };
    float* hA    = (float*)alloc((size_t)NN * NH * 4);
    float* Qn    = (float*)alloc((size_t)NN * NH * 4);      // att aliases this (E1..E2a window)
    float* Kn    = (float*)alloc((size_t)NN * NH * 4);      // aggr aliases this (E2b..Wa window)
    float* Vn    = (float*)alloc((size_t)NN * NH * 4);
    float* QA    = (float*)alloc((size_t)NREL * NN * NH * 4);  // P aliases this (E2a..E2b)
    float* rtab  = (float*)alloc((size_t)240 * NH * 4);
    float* RK    = (float*)alloc((size_t)NTYPE * 240 * NH * 4);
    float* RV    = (float*)alloc((size_t)NTYPE * 240 * NH * 4);
    int* nperm   = (int*)alloc((size_t)NTYPE * NN * 4);
    int* rowptr  = (int*)alloc((size_t)(NN + 1) * 4);
    int* csr_e   = (int*)alloc((size_t)NE * 4);
    int* deg     = (int*)alloc((size_t)2 * NN * 4);   // deg+cursor in ONE block: the single
    int* cursor  = deg + NN;                          // memset covers both exactly
    int* bsum    = (int*)alloc(256 * 4);
    int* bbase   = (int*)alloc(256 * 4);
    int* ncur    = (int*)alloc(64);
    float* att   = Qn;      // [NE*NHEAD] = 6.4 MB < 25.6 MB
    float* Pbuf  = QA;      // per-(relation,node) aggregate
    float* aggr  = Kn;

    hipMemsetAsync(ncur, 0, 64, stream);
    hipMemsetAsync(deg, 0, (size_t)2 * NN * 4, stream);     // covers deg AND cursor exactly

    GNN_nscatter<<<(NN + 255) / 256, 256, 0, stream>>>(node_type, ncur, nperm);
    GNN_deg<<<(NE + 255) / 256, 256, 0, stream>>>(edst, deg);
    GNN_scan1<<<NSCAN_BLK, 256, 0, stream>>>(deg, rowptr, bsum);
    GNN_scan2<<<1, 256, 0, stream>>>(bsum, bbase);
    GNN_scan3<<<NSCAN_BLK, 256, 0, stream>>>(rowptr, bbase);
    GNN_csr_scatter<<<(NE + 255) / 256, 256, 0, stream>>>(edst, rowptr, cursor, csr_e);

    dim3 ggrid((NN + BN - 1) / BN, NTYPE);
    GNN_ptype_gemm<0><<<ggrid, 256, 0, stream>>>(node_feature, INDIM, adapt_W, adapt_b,
                                                 nullptr, nullptr, nperm, ncur, hA);
    const float* hin = hA;
    for (int l = 0; l < 2; l++){
        const float* WkL = Wk + (size_t)l * NTYPE * NH * NH;
        const float* WqL = Wq + (size_t)l * NTYPE * NH * NH;
        const float* WvL = Wv + (size_t)l * NTYPE * NH * NH;
        const float* WaL = Wa + (size_t)l * NTYPE * NH * NH;
        const float* bkL = bk + (size_t)l * NTYPE * NH;
        const float* bqL = bq + (size_t)l * NTYPE * NH;
        const float* bvL = bv + (size_t)l * NTYPE * NH;
        const float* baL = ba + (size_t)l * NTYPE * NH;
        const float* relA = rel_att + (size_t)l * NREL * NHEAD * DK * DK;
        const float* relM = rel_msg + (size_t)l * NREL * NHEAD * DK * DK;
        const float* relP = rel_pri + (size_t)l * NREL * NHEAD;

        GNN_rte_tab<<<240, 128, 0, stream>>>(rte_emb, rte_W + (size_t)l * NH * NH,
                                             rte_b + (size_t)l * NH, rtab);
        GNN_rte_proj<<<dim3(240, NTYPE * 2), 128, 0, stream>>>(rtab, WkL, WvL, RK, RV);

        GNN_qkv_gemm<<<dim3(ggrid.x, NTYPE, 3), 256, 0, stream>>>(
            hin, WqL, bqL, WkL, bkL, WvL, bvL, nperm, ncur, Qn, Kn, Vn);

        GNN_qa<<<dim3((NN + 63) / 64, NREL), 256, 0, stream>>>(Qn, relA, QA);

        GNN_edge_att<<<(NE + 7) / 8, 256, 0, stream>>>(
            Kn, RK, QA, esrc, edst, edge_type, edge_time, node_type, relP, att);

        GNN_node_aggr<<<(NN + 7) / 8, 256, 0, stream>>>(
            att, Vn, RV, rowptr, csr_e, esrc, edge_type, edge_time, node_type, Pbuf);

        GNN_pm<<<(NN + 63) / 64, 256, 0, stream>>>(Pbuf, relM, aggr);

        float* hout = (l == 0) ? hA : (float*)d_out;   // l==0 in-place on hA is safe:
        GNN_ptype_gemm<2><<<ggrid, 256, 0, stream>>>(  // epilogue reads Hprev[nid,cols] then
            aggr, NH, WaL, baL, skip + (size_t)l * NTYPE, hin,   // writes same elems, same thread
            nperm, ncur, hout);
        hin = hout;
    }
}

// Round 5
// 1097.366 us; speedup vs baseline: 3.0840x; 1.0327x over previous
//
#include <hip/hip_runtime.h>
#include <math.h>

// ---- problem constants ----
#define NN     50000
#define NE     400000
#define INDIM  256
#define NH     128
#define NTYPE  4
#define NREL   5
#define NHEAD  4
#define DK     32
#define RSQRT_DK 0.17677669529663687f
#define BN     64
#define NSCAN_BLK ((NN + 255) / 256)   // 196
#define XB     260                     // Xs c4-block stride in words (260*4B, 16B-aligned)

__device__ __forceinline__ float gelu_f(float x){
    return 0.5f * x * (1.0f + erff(x * 0.70710678118654752f));
}

// ---------------- node bucketing by type (for per-type GEMMs) ----------------
__global__ void GNN_nscatter(const int* __restrict__ ntype, int* __restrict__ ncur,
                             int* __restrict__ nperm){
    __shared__ int lcnt[4], lbase[4];
    int tid = threadIdx.x;
    if (tid < 4) lcnt[tid] = 0;
    __syncthreads();
    int n = blockIdx.x * 256 + tid;
    int t = 0, lpos = 0;
    bool ok = (n < NN);
    if (ok){ t = ntype[n]; lpos = atomicAdd(&lcnt[t], 1); }
    __syncthreads();
    if (tid < 4 && lcnt[tid] > 0) lbase[tid] = atomicAdd(&ncur[tid], lcnt[tid]);
    __syncthreads();
    if (ok) nperm[t * NN + lbase[t] + lpos] = n;
}

// ---------------- CSR by destination (built once per call) ----------------
__global__ void GNN_deg(const int* __restrict__ edst, int* __restrict__ deg){
    int e = blockIdx.x * 256 + threadIdx.x;
    if (e < NE) atomicAdd(&deg[edst[e]], 1);
}

__global__ void GNN_scan1(const int* __restrict__ deg, int* __restrict__ rowptr,
                          int* __restrict__ bsum){
    __shared__ int s[256];
    int g = blockIdx.x * 256 + threadIdx.x;
    int v = (g < NN) ? deg[g] : 0;
    s[threadIdx.x] = v;
    __syncthreads();
    for (int off = 1; off < 256; off <<= 1){
        int t = (threadIdx.x >= off) ? s[threadIdx.x - off] : 0;
        __syncthreads();
        s[threadIdx.x] += t;
        __syncthreads();
    }
    if (g < NN) rowptr[g] = s[threadIdx.x] - v;           // block-local exclusive
    if (threadIdx.x == 255) bsum[blockIdx.x] = s[255];
}

__global__ void GNN_scan2(const int* __restrict__ bsum, int* __restrict__ bbase){
    __shared__ int s[256];
    int v = (threadIdx.x < NSCAN_BLK) ? bsum[threadIdx.x] : 0;
    s[threadIdx.x] = v;
    __syncthreads();
    for (int off = 1; off < 256; off <<= 1){
        int t = (threadIdx.x >= off) ? s[threadIdx.x - off] : 0;
        __syncthreads();
        s[threadIdx.x] += t;
        __syncthreads();
    }
    bbase[threadIdx.x] = s[threadIdx.x] - v;              // exclusive
}

__global__ void GNN_scan3(int* __restrict__ rowptr, const int* __restrict__ bbase){
    int g = blockIdx.x * 256 + threadIdx.x;
    if (g < NN) rowptr[g] += bbase[blockIdx.x];
    if (g == 0) rowptr[NN] = NE;
}

__global__ void GNN_csr_scatter(const int* __restrict__ edst, const int* __restrict__ rowptr,
                                int* __restrict__ cursor, int* __restrict__ csr_e){
    int e = blockIdx.x * 256 + threadIdx.x;
    if (e >= NE) return;
    int d = edst[e];
    int pos = atomicAdd(&cursor[d], 1);
    csr_e[rowptr[d] + pos] = e;
}

// ------------- shared GEMM tile core: 256 threads, 64 rows x 128 cols, 8x4 per thread.
// Xs layout: c4-block-major, word = c4*XB + row*4.  Ws: [32][128] contiguous.
// v5: T14 software pipeline — next k-tile held in 6 NAMED float4 regs (no arrays ->
//   no scratch, rule-20), issued right after the barrier so the ~600cy global latency
//   hides under the ~2Kcy compute phase. acc stays 8x4 (32 regs) -> no round-2 spill.
template<int MODE>
__device__ __forceinline__ void gemm_tile(
    const float* __restrict__ X, int K,
    const float* __restrict__ W, const float* __restrict__ brow,
    float a_t, const float* __restrict__ Hprev,
    float* Xs, float* Ws, const int* nids,
    float* __restrict__ OUT)
{
    int tid = threadIdx.x;
    int cq = tid & 31, rq = tid >> 5;

    // fixed per-thread staging coordinates
    int xc0 = tid >> 6,          xr0i = tid & 63;         // X slot j=0
    int xc1 = (256 + tid) >> 6,  xr1i = tid & 63;         // X slot j=1 (c4 = xc0+4)
    int nid0 = nids[xr0i], nid1 = nids[xr1i];
    const float* xp0 = (nid0 >= 0) ? X + (size_t)nid0 * K + xc0 * 4 : nullptr;
    const float* xp1 = (nid1 >= 0) ? X + (size_t)nid1 * K + xc1 * 4 : nullptr;
    int wk = tid >> 5, wc4 = (tid & 31) * 4;              // W slots: kk = wk + 8j

    float4 xr0, xr1, wr0, wr1, wr2, wr3;
    const float4 z4 = make_float4(0.f, 0.f, 0.f, 0.f);

    #define LOADREGS(k0)                                                        \
        xr0 = xp0 ? *(const float4*)(xp0 + (k0)) : z4;                          \
        xr1 = xp1 ? *(const float4*)(xp1 + (k0)) : z4;                          \
        wr0 = *(const float4*)(W + (size_t)((k0) + wk     ) * NH + wc4);        \
        wr1 = *(const float4*)(W + (size_t)((k0) + wk +  8) * NH + wc4);        \
        wr2 = *(const float4*)(W + (size_t)((k0) + wk + 16) * NH + wc4);        \
        wr3 = *(const float4*)(W + (size_t)((k0) + wk + 24) * NH + wc4);

    #define WRITELDS()                                                          \
        *(float4*)&Xs[xc0 * XB + xr0i * 4] = xr0;                               \
        *(float4*)&Xs[xc1 * XB + xr1i * 4] = xr1;                               \
        *(float4*)&Ws[(wk     ) * 128 + wc4] = wr0;                             \
        *(float4*)&Ws[(wk +  8) * 128 + wc4] = wr1;                             \
        *(float4*)&Ws[(wk + 16) * 128 + wc4] = wr2;                             \
        *(float4*)&Ws[(wk + 24) * 128 + wc4] = wr3;

    float acc[8][4];
    #pragma unroll
    for (int i = 0; i < 8; i++){ acc[i][0]=0.f; acc[i][1]=0.f; acc[i][2]=0.f; acc[i][3]=0.f; }

    LOADREGS(0);
    for (int k0 = 0; k0 < K; k0 += 32){
        WRITELDS();
        __syncthreads();
        if (k0 + 32 < K){ LOADREGS(k0 + 32); }          // issue-early: hides under compute
        #pragma unroll 2
        for (int c4 = 0; c4 < 8; c4++){
            float4 w0 = *(const float4*)&Ws[(c4*4+0)*128 + cq*4];
            float4 w1 = *(const float4*)&Ws[(c4*4+1)*128 + cq*4];
            float4 w2 = *(const float4*)&Ws[(c4*4+2)*128 + cq*4];
            float4 w3 = *(const float4*)&Ws[(c4*4+3)*128 + cq*4];
            #pragma unroll
            for (int i = 0; i < 8; i++){
                float4 xv = *(const float4*)&Xs[c4 * XB + (rq + 8*i) * 4];
                acc[i][0] += xv.x*w0.x + xv.y*w1.x + xv.z*w2.x + xv.w*w3.x;
                acc[i][1] += xv.x*w0.y + xv.y*w1.y + xv.z*w2.y + xv.w*w3.y;
                acc[i][2] += xv.x*w0.z + xv.y*w1.z + xv.z*w2.z + xv.w*w3.z;
                acc[i][3] += xv.x*w0.w + xv.y*w1.w + xv.z*w2.w + xv.w*w3.w;
            }
        }
        __syncthreads();
    }
    #undef LOADREGS
    #undef WRITELDS

    float4 b4 = *(const float4*)(brow + cq * 4);
    float one_m = 1.f - a_t;
    #pragma unroll
    for (int i = 0; i < 8; i++){
        int r = rq + 8*i;
        int nid = nids[r];
        if (nid < 0) continue;
        float v0 = acc[i][0] + b4.x, v1 = acc[i][1] + b4.y;
        float v2 = acc[i][2] + b4.z, v3 = acc[i][3] + b4.w;
        if (MODE == 0){ v0 = gelu_f(v0); v1 = gelu_f(v1); v2 = gelu_f(v2); v3 = gelu_f(v3); }
        if (MODE == 2){
            float4 hp = *(const float4*)(Hprev + (size_t)nid * NH + cq * 4);
            v0 = v0 * a_t + hp.x * one_m; v1 = v1 * a_t + hp.y * one_m;
            v2 = v2 * a_t + hp.z * one_m; v3 = v3 * a_t + hp.w * one_m;
        }
        *(float4*)(OUT + (size_t)nid * NH + cq * 4) = make_float4(v0, v1, v2, v3);
    }
}

// ------------- per-type tiled GEMM: OUT[n,:] = epilogue( X[n,:] @ W[type(n)] + b[type(n)] )
// MODE 0: gelu(.)   MODE 1: identity   MODE 2: (.)*sig(skip[t]) + Hprev*(1-sig(skip[t]))
template<int MODE>
__global__ __launch_bounds__(256) void GNN_ptype_gemm(
    const float* __restrict__ X, int K,
    const float* __restrict__ Wall, const float* __restrict__ ball,
    const float* __restrict__ skiprow, const float* __restrict__ Hprev,
    const int* __restrict__ nperm, const int* __restrict__ counts,
    float* __restrict__ OUT)
{
    int t = blockIdx.y;
    int cnt = counts[t];
    int rbase = blockIdx.x * BN;
    if (rbase >= cnt) return;
    __shared__ float Xs[8 * XB];
    __shared__ float Ws[32 * 128];
    __shared__ int nids[BN];
    int tid = threadIdx.x;
    if (tid < BN){
        int idx = rbase + tid;
        nids[tid] = (idx < cnt) ? nperm[t * NN + idx] : -1;
    }
    __syncthreads();
    float a_t = 0.f;
    if (MODE == 2) a_t = 1.f / (1.f + expf(-skiprow[t]));
    gemm_tile<MODE>(X, K, Wall + (size_t)t * K * NH, ball + t * NH,
                    a_t, Hprev, Xs, Ws, nids, OUT);
}

// ------------- fused Q/K/V projections: blockIdx.z selects which (3x occupancy) ---------
__global__ __launch_bounds__(256) void GNN_qkv_gemm(
    const float* __restrict__ X,
    const float* __restrict__ Wq, const float* __restrict__ bq,
    const float* __restrict__ Wk, const float* __restrict__ bk,
    const float* __restrict__ Wv, const float* __restrict__ bv,
    const int* __restrict__ nperm, const int* __restrict__ counts,
    float* __restrict__ Qn, float* __restrict__ Kn, float* __restrict__ Vn)
{
    int t = blockIdx.y;
    int cnt = counts[t];
    int rbase = blockIdx.x * BN;
    if (rbase >= cnt) return;
    __shared__ float Xs[8 * XB];
    __shared__ float Ws[32 * 128];
    __shared__ int nids[BN];
    int tid = threadIdx.x;
    if (tid < BN){
        int idx = rbase + tid;
        nids[tid] = (idx < cnt) ? nperm[t * NN + idx] : -1;
    }
    __syncthreads();
    int z = blockIdx.z;
    const float* W = (z == 0) ? Wq : (z == 1) ? Wk : Wv;
    const float* b = (z == 0) ? bq : (z == 1) ? bk : bv;
    float* OUT     = (z == 0) ? Qn : (z == 1) ? Kn : Vn;
    gemm_tile<1>(X, NH, W + (size_t)t * NH * NH, b + t * NH,
                 0.f, nullptr, Xs, Ws, nids, OUT);
}

// ------------- RTE tables ----------------
__global__ void GNN_rte_tab(const float* __restrict__ rte_emb, const float* __restrict__ rW,
                            const float* __restrict__ rb, float* __restrict__ tab){
    int m = blockIdx.x, j = threadIdx.x;
    __shared__ float e[NH];
    e[j] = rte_emb[m * NH + j];
    __syncthreads();
    float a = rb[j];
    #pragma unroll 8
    for (int d = 0; d < NH; d++) a += e[d] * rW[d * NH + j];
    tab[m * NH + j] = a;
}

__global__ void GNN_rte_proj(const float* __restrict__ tab, const float* __restrict__ WkL,
                             const float* __restrict__ WvL, float* __restrict__ RK,
                             float* __restrict__ RV){
    int m = blockIdx.x, j = threadIdx.x;
    int sel = blockIdx.y; int t = sel >> 1; int which = sel & 1;
    const float* W = (which ? WvL : WkL) + (size_t)t * NH * NH;
    float* O = which ? RV : RK;
    __shared__ float e[NH];
    e[j] = tab[m * NH + j];
    __syncthreads();
    float a = 0.f;
    #pragma unroll 8
    for (int d = 0; d < NH; d++) a += e[d] * W[d * NH + j];
    O[(size_t)(t * 240 + m) * NH + j] = a;
}

// ------------- QA[r][i][h*32+d] = sum_c rel_att[r][h][d][c] * q[i][h*32+c] -----------
// v2: no Q LDS tile — Q read as 8-lane-broadcast float4 from global inside the FMA loop
// (address independent of q=cq&7). Atp stays in LDS (17 KB), ONE barrier per block.
//   Atp word index = h*1072 + (d>>2)*132 + c*4 + (d&3)
__global__ __launch_bounds__(256) void GNN_qa(
    const float* __restrict__ Qn, const float* __restrict__ relA, float* __restrict__ QA)
{
    __shared__ float Atp[4 * 1072];        // 17152 B
    int r = blockIdx.y;
    int nb = blockIdx.x * 64;
    int tid = threadIdx.x;
    const float* Ar = relA + (size_t)r * NHEAD * DK * DK;
    for (int x = tid; x < NHEAD * DK * DK; x += 256){
        int hh = x >> 10, rem = x & 1023, dd = rem >> 5, cc = rem & 31;
        Atp[hh * 1072 + (dd >> 2) * 132 + cc * 4 + (dd & 3)] = Ar[x];
    }
    __syncthreads();
    int cq = tid & 31, rq = tid >> 5;
    int h = cq >> 3;
    int abase = h * 1072 + (cq & 7) * 132;
    int rowoff[8];
    #pragma unroll
    for (int i = 0; i < 8; i++){
        int node = nb + rq + 8*i;
        if (node >= NN) node = NN - 1;              // clamp: write is guarded below
        rowoff[i] = node * NH + h * 32;
    }
    float acc[8][4];
    #pragma unroll
    for (int i = 0; i < 8; i++){ acc[i][0]=0.f; acc[i][1]=0.f; acc[i][2]=0.f; acc[i][3]=0.f; }
    #pragma unroll 2
    for (int c4 = 0; c4 < 8; c4++){
        float4 av0 = *(const float4*)&Atp[abase + c4 * 16 + 0];
        float4 av1 = *(const float4*)&Atp[abase + c4 * 16 + 4];
        float4 av2 = *(const float4*)&Atp[abase + c4 * 16 + 8];
        float4 av3 = *(const float4*)&Atp[abase + c4 * 16 + 12];
        #pragma unroll
        for (int i = 0; i < 8; i++){
            float4 qv = *(const float4*)(Qn + rowoff[i] + c4 * 4);
            acc[i][0] += qv.x*av0.x + qv.y*av1.x + qv.z*av2.x + qv.w*av3.x;
            acc[i][1] += qv.x*av0.y + qv.y*av1.y + qv.z*av2.y + qv.w*av3.y;
            acc[i][2] += qv.x*av0.z + qv.y*av1.z + qv.z*av2.z + qv.w*av3.z;
            acc[i][3] += qv.x*av0.w + qv.y*av1.w + qv.z*av2.w + qv.w*av3.w;
        }
    }
    #pragma unroll
    for (int i = 0; i < 8; i++){
        int node = nb + rq + 8*i;
        if (node >= NN) continue;
        *(float4*)(QA + ((size_t)r * NN + node) * NH + cq * 4) =
            make_float4(acc[i][0], acc[i][1], acc[i][2], acc[i][3]);
    }
}

// ------------- E1: att[e,h] = (Kn[src]+RK[st,tm]) . QA[r][dst]  (32 lanes/edge, no LDS) ----
__global__ __launch_bounds__(256) void GNN_edge_att(
    const float* __restrict__ Kn, const float* __restrict__ RK, const float* __restrict__ QA,
    const int* __restrict__ esrc, const int* __restrict__ edst,
    const int* __restrict__ etype, const int* __restrict__ etime,
    const int* __restrict__ ntype, const float* __restrict__ relP,
    float* __restrict__ att)
{
    int tid = threadIdx.x;
    int e = blockIdx.x * 8 + (tid >> 5);
    if (e >= NE) return;
    int lane = tid & 31;
    int s = esrc[e], d = edst[e], r = etype[e], tm = etime[e];
    int st = ntype[s];
    float4 k4 = *(const float4*)(Kn + (size_t)s * NH + lane * 4);
    float4 rk = *(const float4*)(RK + (size_t)(st * 240 + tm) * NH + lane * 4);
    float4 qa = *(const float4*)(QA + ((size_t)r * NN + d) * NH + lane * 4);
    float pv = (k4.x + rk.x) * qa.x + (k4.y + rk.y) * qa.y
             + (k4.z + rk.z) * qa.z + (k4.w + rk.w) * qa.w;
    pv += __shfl_xor(pv, 4);
    pv += __shfl_xor(pv, 2);
    pv += __shfl_xor(pv, 1);
    if ((lane & 7) == 0){
        int head = lane >> 3;
        att[(size_t)e * NHEAD + head] = pv * relP[r * NHEAD + head] * RSQRT_DK;
    }
}

// ------------- E2a: per-node softmax + per-relation aggregation of raw v (no atomics) -----
__global__ __launch_bounds__(256) void GNN_node_aggr(
    const float* __restrict__ att, const float* __restrict__ Vn, const float* __restrict__ RV,
    const int* __restrict__ rowptr, const int* __restrict__ csr_e,
    const int* __restrict__ esrc, const int* __restrict__ etype,
    const int* __restrict__ etime, const int* __restrict__ ntype,
    float* __restrict__ P)
{
    int tid = threadIdx.x;
    int i = blockIdx.x * 8 + (tid >> 5);
    if (i >= NN) return;
    int lane = tid & 31;
    int head = lane >> 3;
    int beg = rowptr[i], end = rowptr[i + 1];
    // pass 1: segment max (all 8 lanes of a head read the same att value)
    float mx = -3.4e38f;
    for (int k = beg; k < end; k++){
        int e = csr_e[k];
        mx = fmaxf(mx, att[(size_t)e * NHEAD + head]);
    }
    // pass 2: accumulate exp-weighted raw v per relation, in registers
    float4 acc[NREL];
    #pragma unroll
    for (int rr = 0; rr < NREL; rr++) acc[rr] = make_float4(0.f, 0.f, 0.f, 0.f);
    float den = 0.f;
    for (int k = beg; k < end; k++){
        int e = csr_e[k];
        int s = esrc[e], r = etype[e], tm = etime[e];
        int st = ntype[s];
        float ex = expf(att[(size_t)e * NHEAD + head] - mx);
        den += ex;
        float4 v4 = *(const float4*)(Vn + (size_t)s * NH + lane * 4);
        float4 rv = *(const float4*)(RV + (size_t)(st * 240 + tm) * NH + lane * 4);
        float vx = v4.x + rv.x, vy = v4.y + rv.y, vz = v4.z + rv.z, vw = v4.w + rv.w;
        #pragma unroll
        for (int rr = 0; rr < NREL; rr++){
            float w = (rr == r) ? ex : 0.f;     // predicated, keeps acc in registers
            acc[rr].x += w * vx; acc[rr].y += w * vy;
            acc[rr].z += w * vz; acc[rr].w += w * vw;
        }
    }
    float inv = 1.f / (den + 1e-16f);
    #pragma unroll
    for (int rr = 0; rr < NREL; rr++){
        *(float4*)(P + ((size_t)rr * NN + i) * NH + lane * 4) =
            make_float4(acc[rr].x * inv, acc[rr].y * inv, acc[rr].z * inv, acc[rr].w * inv);
    }
}

// ------------- E2b: aggr[i][h*32+c] = gelu( sum_r sum_d P[r][i][h*32+d] * M_r[h][d][c] ) ---
// v2: no Ps LDS tile — P read as 8-lane-broadcast float4 from global in the FMA loop.
// Msp double-buffered in LDS with register prefetch of M(r+1) under compute of r (T14).
__global__ __launch_bounds__(256) void GNN_pm(
    const float* __restrict__ P, const float* __restrict__ relM, float* __restrict__ aggr)
{
    __shared__ float Msp[2][4 * 1072];     // 2 x 17152 B
    int tid = threadIdx.x;
    int nb = blockIdx.x * 64;
    int cq = tid & 31, rq = tid >> 5;
    int h = cq >> 3;
    int mbase = h * 1072 + (cq & 7) * 132;
    int rowoff[8];
    #pragma unroll
    for (int i = 0; i < 8; i++){
        int node = nb + rq + 8*i;
        if (node >= NN) node = NN - 1;              // clamp: write is guarded below
        rowoff[i] = node * NH + h * 32;
    }
    float acc[8][4];
    #pragma unroll
    for (int i = 0; i < 8; i++){ acc[i][0]=0.f; acc[i][1]=0.f; acc[i][2]=0.f; acc[i][3]=0.f; }

    // prologue: stage M(0) into buffer 0
    #pragma unroll
    for (int j = 0; j < 4; j++){
        int s = tid + 256 * j;
        float4 mv = *(const float4*)(relM + 4 * s);
        *(float4*)&Msp[0][(s >> 8) * 1072 + (s & 7) * 132 + ((s >> 3) & 31) * 4] = mv;
    }
    __syncthreads();

    #pragma unroll
    for (int r = 0; r < NREL; r++){
        float4 mpre[4];
        if (r + 1 < NREL){                           // prefetch next M under compute
            const float* Mn = relM + (size_t)(r + 1) * NHEAD * DK * DK;
            #pragma unroll
            for (int j = 0; j < 4; j++)
                mpre[j] = *(const float4*)(Mn + 4 * (tid + 256 * j));
        }
        const float* Ms = Msp[r & 1];
        const float* Pr = P + (size_t)r * NN * NH;
        #pragma unroll 2
        for (int d4 = 0; d4 < 8; d4++){
            float4 mv0 = *(const float4*)&Ms[mbase + d4 * 16 + 0];
            float4 mv1 = *(const float4*)&Ms[mbase + d4 * 16 + 4];
            float4 mv2 = *(const float4*)&Ms[mbase + d4 * 16 + 8];
            float4 mv3 = *(const float4*)&Ms[mbase + d4 * 16 + 12];
            #pragma unroll
            for (int i = 0; i < 8; i++){
                float4 pv = *(const float4*)(Pr + rowoff[i] + d4 * 4);
                acc[i][0] += pv.x*mv0.x + pv.y*mv1.x + pv.z*mv2.x + pv.w*mv3.x;
                acc[i][1] += pv.x*mv0.y + pv.y*mv1.y + pv.z*mv2.y + pv.w*mv3.y;
                acc[i][2] += pv.x*mv0.z + pv.y*mv1.z + pv.z*mv2.z + pv.w*mv3.z;
                acc[i][3] += pv.x*mv0.w + pv.y*mv1.w + pv.z*mv2.w + pv.w*mv3.w;
            }
        }
        if (r + 1 < NREL){
            #pragma unroll
            for (int j = 0; j < 4; j++){
                int s = tid + 256 * j;
                *(float4*)&Msp[(r + 1) & 1][(s >> 8) * 1072 + (s & 7) * 132 +
                                            ((s >> 3) & 31) * 4] = mpre[j];
            }
            __syncthreads();
        }
    }
    #pragma unroll
    for (int i = 0; i < 8; i++){
        int node = nb + rq + 8*i;
        if (node >= NN) continue;
        *(float4*)(aggr + (size_t)node * NH + cq * 4) =
            make_float4(gelu_f(acc[i][0]), gelu_f(acc[i][1]),
                        gelu_f(acc[i][2]), gelu_f(acc[i][3]));
    }
}

extern "C" void kernel_launch(void* const* d_in, const int* in_sizes, int n_in,
                              void* d_out, int out_size, void* d_ws, size_t ws_size,
                              hipStream_t stream)
{
    const float* node_feature = (const float*)d_in[0];
    const float* adapt_W = (const float*)d_in[1];
    const float* adapt_b = (const float*)d_in[2];
    const float* Wk = (const float*)d_in[3];
    const float* bk = (const float*)d_in[4];
    const float* Wq = (const float*)d_in[5];
    const float* bq = (const float*)d_in[6];
    const float* Wv = (const float*)d_in[7];
    const float* bv = (const float*)d_in[8];
    const float* Wa = (const float*)d_in[9];
    const float* ba = (const float*)d_in[10];
    const float* rel_pri = (const float*)d_in[11];
    const float* rel_att = (const float*)d_in[12];
    const float* rel_msg = (const float*)d_in[13];
    const float* skip = (const float*)d_in[14];
    const float* rte_emb = (const float*)d_in[15];
    const float* rte_W = (const float*)d_in[16];
    const float* rte_b = (const float*)d_in[17];
    const int* node_type = (const int*)d_in[18];
    const int* edge_index = (const int*)d_in[19];
    const int* edge_type = (const int*)d_in[20];
    const int* edge_time = (const int*)d_in[21];
    const int* esrc = edge_index;          // row 0 = source j
    const int* edst = edge_index + NE;     // row 1 = target i

    char* p = (char*)d_ws;
    auto alloc = [&](size_t bytes) -> char* {
        char* r = p; p += (bytes + 255) & ~(size_t)255; return r;
    };
    float* hA    = (float*)alloc((size_t)NN * NH * 4);
    float* Qn    = (float*)alloc((size_t)NN * NH * 4);      // att aliases this (E1..E2a window)
    float* Kn    = (float*)alloc((size_t)NN * NH * 4);      // aggr aliases this (E2b..Wa window)
    float* Vn    = (float*)alloc((size_t)NN * NH * 4);
    float* QA    = (float*)alloc((size_t)NREL * NN * NH * 4);  // P aliases this (E2a..E2b)
    float* rtab  = (float*)alloc((size_t)240 * NH * 4);
    float* RK    = (float*)alloc((size_t)NTYPE * 240 * NH * 4);
    float* RV    = (float*)alloc((size_t)NTYPE * 240 * NH * 4);
    int* nperm   = (int*)alloc((size_t)NTYPE * NN * 4);
    int* rowptr  = (int*)alloc((size_t)(NN + 1) * 4);
    int* csr_e   = (int*)alloc((size_t)NE * 4);
    int* deg     = (int*)alloc((size_t)2 * NN * 4);   // deg+cursor in ONE block: the single
    int* cursor  = deg + NN;                          // memset covers both exactly
    int* bsum    = (int*)alloc(256 * 4);
    int* bbase   = (int*)alloc(256 * 4);
    int* ncur    = (int*)alloc(64);
    float* att   = Qn;      // [NE*NHEAD] = 6.4 MB < 25.6 MB
    float* Pbuf  = QA;      // per-(relation,node) aggregate
    float* aggr  = Kn;

    hipMemsetAsync(ncur, 0, 64, stream);
    hipMemsetAsync(deg, 0, (size_t)2 * NN * 4, stream);     // covers deg AND cursor exactly

    GNN_nscatter<<<(NN + 255) / 256, 256, 0, stream>>>(node_type, ncur, nperm);
    GNN_deg<<<(NE + 255) / 256, 256, 0, stream>>>(edst, deg);
    GNN_scan1<<<NSCAN_BLK, 256, 0, stream>>>(deg, rowptr, bsum);
    GNN_scan2<<<1, 256, 0, stream>>>(bsum, bbase);
    GNN_scan3<<<NSCAN_BLK, 256, 0, stream>>>(rowptr, bbase);
    GNN_csr_scatter<<<(NE + 255) / 256, 256, 0, stream>>>(edst, rowptr, cursor, csr_e);

    dim3 ggrid((NN + BN - 1) / BN, NTYPE);
    GNN_ptype_gemm<0><<<ggrid, 256, 0, stream>>>(node_feature, INDIM, adapt_W, adapt_b,
                                                 nullptr, nullptr, nperm, ncur, hA);
    const float* hin = hA;
    for (int l = 0; l < 2; l++){
        const float* WkL = Wk + (size_t)l * NTYPE * NH * NH;
        const float* WqL = Wq + (size_t)l * NTYPE * NH * NH;
        const float* WvL = Wv + (size_t)l * NTYPE * NH * NH;
        const float* WaL = Wa + (size_t)l * NTYPE * NH * NH;
        const float* bkL = bk + (size_t)l * NTYPE * NH;
        const float* bqL = bq + (size_t)l * NTYPE * NH;
        const float* bvL = bv + (size_t)l * NTYPE * NH;
        const float* baL = ba + (size_t)l * NTYPE * NH;
        const float* relA = rel_att + (size_t)l * NREL * NHEAD * DK * DK;
        const float* relM = rel_msg + (size_t)l * NREL * NHEAD * DK * DK;
        const float* relP = rel_pri + (size_t)l * NREL * NHEAD;

        GNN_rte_tab<<<240, 128, 0, stream>>>(rte_emb, rte_W + (size_t)l * NH * NH,
                                             rte_b + (size_t)l * NH, rtab);
        GNN_rte_proj<<<dim3(240, NTYPE * 2), 128, 0, stream>>>(rtab, WkL, WvL, RK, RV);

        GNN_qkv_gemm<<<dim3(ggrid.x, NTYPE, 3), 256, 0, stream>>>(
            hin, WqL, bqL, WkL, bkL, WvL, bvL, nperm, ncur, Qn, Kn, Vn);

        GNN_qa<<<dim3((NN + 63) / 64, NREL), 256, 0, stream>>>(Qn, relA, QA);

        GNN_edge_att<<<(NE + 7) / 8, 256, 0, stream>>>(
            Kn, RK, QA, esrc, edst, edge_type, edge_time, node_type, relP, att);

        GNN_node_aggr<<<(NN + 7) / 8, 256, 0, stream>>>(
            att, Vn, RV, rowptr, csr_e, esrc, edge_type, edge_time, node_type, Pbuf);

        GNN_pm<<<(NN + 63) / 64, 256, 0, stream>>>(Pbuf, relM, aggr);

        float* hout = (l == 0) ? hA : (float*)d_out;   // l==0 in-place on hA is safe:
        GNN_ptype_gemm<2><<<ggrid, 256, 0, stream>>>(  // epilogue reads Hprev[nid,cols] then
            aggr, NH, WaL, baL, skip + (size_t)l * NTYPE, hin,   // writes same elems, same thread
            nperm, ncur, hout);
        hin = hout;
    }
}